// Round 3
// baseline (534.875 us; speedup 1.0000x reference)
//
#include <hip/hip_runtime.h>

#define D_MODEL 1024
#define SEQ     2048
#define BATCH   2
#define NHEADS  16
#define DK      64
#define NROWS   (BATCH*SEQ)   // 4096

typedef unsigned short u16;
typedef __bf16 bf16x8 __attribute__((ext_vector_type(8)));
typedef float  f32x4  __attribute__((ext_vector_type(4)));

__device__ __forceinline__ u16 f2bf(float f) {
    union { float f; unsigned u; } v; v.f = f;
    unsigned u = v.u;
    u += 0x7fffu + ((u >> 16) & 1);   // round-to-nearest-even
    return (u16)(u >> 16);
}
__device__ __forceinline__ float bf2f(u16 h) {
    union { unsigned u; float f; } v; v.u = ((unsigned)h) << 16;
    return v.f;
}

// ---------- f32 [R][1024] -> bf16 split [R][2048] = [hi(1024) | lo(1024)] ----------
__global__ void cvt_split(const float* __restrict__ src, u16* __restrict__ dst, int total4) {
    int i = blockIdx.x * blockDim.x + threadIdx.x;
    if (i >= total4) return;
    int row = i >> 8;            // 256 float4 chunks per 1024-row
    int c   = (i & 255) * 4;
    float4 v = *(const float4*)(src + (size_t)row * 1024 + c);
    u16 h0 = f2bf(v.x), h1 = f2bf(v.y), h2 = f2bf(v.z), h3 = f2bf(v.w);
    u16 l0 = f2bf(v.x - bf2f(h0)), l1 = f2bf(v.y - bf2f(h1));
    u16 l2 = f2bf(v.z - bf2f(h2)), l3 = f2bf(v.w - bf2f(h3));
    size_t b = (size_t)row * 2048;
    uint2 ph; ph.x = h0 | ((unsigned)h1 << 16); ph.y = h2 | ((unsigned)h3 << 16);
    uint2 pl; pl.x = l0 | ((unsigned)l1 << 16); pl.y = l2 | ((unsigned)l3 << 16);
    *(uint2*)&dst[b + c]        = ph;
    *(uint2*)&dst[b + 1024 + c] = pl;
}

// ---------- split-bf16 GEMM: C[M][1024] = (Ah+Al)[M][1024] * (Bh+Bl)[1024][1024]^T ----
// A2 [M][2048] = [hi|lo], B2 [1024][2048] = [hi|lo]. 3 MFMAs per chunk (hh, lh, hl).
// MODE 0: C split bf16 [M][2048]; MODE 1: C bf16 transposed [1024][M]; MODE 2: C f32 [M][1024].
template<int MODE>
__global__ __launch_bounds__(256) void gemm_split(
    const u16* __restrict__ A2, const u16* __restrict__ B2, void* __restrict__ Cout, int M)
{
    const int N = 1024;
    __shared__ __align__(16) u16 Ash[128 * 40];
    __shared__ __align__(16) u16 Asl[128 * 40];
    __shared__ __align__(16) u16 Bsh[128 * 40];
    __shared__ __align__(16) u16 Bsl[128 * 40];

    const int m0 = blockIdx.x * 128;
    const int n0 = blockIdx.y * 128;
    const int tid = threadIdx.x;
    const int lane = tid & 63;
    const int wid  = tid >> 6;
    const int wr = wid >> 1, wc = wid & 1;
    const int fr = lane & 15;
    const int fk = (lane >> 4) * 8;

    f32x4 acc[4][4];
#pragma unroll
    for (int i = 0; i < 4; ++i)
#pragma unroll
        for (int j = 0; j < 4; ++j) acc[i][j] = (f32x4){0.f, 0.f, 0.f, 0.f};

    for (int k0 = 0; k0 < 1024; k0 += 32) {
        __syncthreads();
#pragma unroll
        for (int s = 0; s < 2; ++s) {
            int c   = tid + s * 256;
            int row = c >> 2;
            int cb  = (c & 3) * 8;
            const u16* ap = A2 + (size_t)(m0 + row) * 2048 + k0 + cb;
            *(uint4*)&Ash[row * 40 + cb] = *(const uint4*)ap;
            *(uint4*)&Asl[row * 40 + cb] = *(const uint4*)(ap + 1024);
            const u16* bp = B2 + (size_t)(n0 + row) * 2048 + k0 + cb;
            *(uint4*)&Bsh[row * 40 + cb] = *(const uint4*)bp;
            *(uint4*)&Bsl[row * 40 + cb] = *(const uint4*)(bp + 1024);
        }
        __syncthreads();

        bf16x8 ah[4], al[4], bh[4], bl[4];
#pragma unroll
        for (int i = 0; i < 4; ++i) {
            ah[i] = *(const bf16x8*)&Ash[(wr * 64 + i * 16 + fr) * 40 + fk];
            al[i] = *(const bf16x8*)&Asl[(wr * 64 + i * 16 + fr) * 40 + fk];
        }
#pragma unroll
        for (int j = 0; j < 4; ++j) {
            bh[j] = *(const bf16x8*)&Bsh[(wc * 64 + j * 16 + fr) * 40 + fk];
            bl[j] = *(const bf16x8*)&Bsl[(wc * 64 + j * 16 + fr) * 40 + fk];
        }
#pragma unroll
        for (int i = 0; i < 4; ++i)
#pragma unroll
            for (int j = 0; j < 4; ++j) {
                acc[i][j] = __builtin_amdgcn_mfma_f32_16x16x32_bf16(ah[i], bh[j], acc[i][j], 0, 0, 0);
                acc[i][j] = __builtin_amdgcn_mfma_f32_16x16x32_bf16(al[i], bh[j], acc[i][j], 0, 0, 0);
                acc[i][j] = __builtin_amdgcn_mfma_f32_16x16x32_bf16(ah[i], bl[j], acc[i][j], 0, 0, 0);
            }
    }

    const int r0 = (lane >> 4) * 4;
#pragma unroll
    for (int i = 0; i < 4; ++i) {
        int row = m0 + wr * 64 + i * 16 + r0;
#pragma unroll
        for (int j = 0; j < 4; ++j) {
            int col = n0 + wc * 64 + j * 16 + fr;
#pragma unroll
            for (int r = 0; r < 4; ++r) {
                float v = acc[i][j][r];
                if (MODE == 0) {
                    u16 hi = f2bf(v);
                    u16 lo = f2bf(v - bf2f(hi));
                    ((u16*)Cout)[(size_t)(row + r) * 2048 + col]        = hi;
                    ((u16*)Cout)[(size_t)(row + r) * 2048 + 1024 + col] = lo;
                } else if (MODE == 1) {
                    ((u16*)Cout)[(size_t)col * M + (row + r)] = f2bf(v);
                } else {
                    ((float*)Cout)[(size_t)(row + r) * N + col] = v;
                }
            }
        }
    }
}

// ---------- RoPE in place on split Q||K: [8192][2048] = [hi(1024)|lo(1024)] per row ----
__global__ void rope_inplace(u16* __restrict__ qk, const int* __restrict__ pos) {
    int i = blockIdx.x * blockDim.x + threadIdx.x;   // 8192 rows * 512 pairs
    int p = i & 511;
    int n = i >> 9;
    int s = n & 2047;
    int k = p & 31;       // pair within head
    int h = p >> 5;       // head
    size_t base = (size_t)n * 2048 + h * DK + 2 * k;
    unsigned vh = *(const unsigned*)&qk[base];
    unsigned vl = *(const unsigned*)&qk[base + 1024];
    float x0 = bf2f((u16)(vh & 0xffff)) + bf2f((u16)(vl & 0xffff));
    float x1 = bf2f((u16)(vh >> 16))    + bf2f((u16)(vl >> 16));
    // angle = pos * theta^(-k/32); ln(10000)/32 = 0.28782313662425575
    float ang = (float)pos[s] * expf((float)k * -0.28782313662425575f);
    float c = cosf(ang), sn = sinf(ang);
    float y0 = x0 * c - x1 * sn;
    float y1 = x1 * c + x0 * sn;
    u16 h0 = f2bf(y0); u16 l0 = f2bf(y0 - bf2f(h0));
    u16 h1 = f2bf(y1); u16 l1 = f2bf(y1 - bf2f(h1));
    *(unsigned*)&qk[base]        = (unsigned)h0 | ((unsigned)h1 << 16);
    *(unsigned*)&qk[base + 1024] = (unsigned)l0 | ((unsigned)l1 << 16);
}

// ---------- causal flash attention (split Q/K scores, bf16 P/V) ----------
// Q2,K2: [4096][2048] split; Vt: [1024][4096] bf16; M2 out: [4096][2048] split.
__global__ __launch_bounds__(256) void attn_kernel(
    const u16* __restrict__ Q2, const u16* __restrict__ K2,
    const u16* __restrict__ Vt, u16* __restrict__ M2)
{
    const int qt = blockIdx.x;     // 0..31
    const int h  = blockIdx.y;     // 0..15
    const int b  = blockIdx.z;     // 0..1
    const int lane = threadIdx.x & 63;
    const int w    = threadIdx.x >> 6;
    const int q0 = qt * 64;
    const int qbase = q0 + w * 16;
    const int fr = lane & 15;
    const int fg = lane >> 4;

    __shared__ __align__(16) u16 Plds[4][16][32];

    const u16* qrowp = Q2 + (size_t)(b * SEQ + qbase + fr) * 2048 + h * DK;
    bf16x8 qh0 = *(const bf16x8*)&qrowp[fg * 8];
    bf16x8 qh1 = *(const bf16x8*)&qrowp[32 + fg * 8];
    bf16x8 ql0 = *(const bf16x8*)&qrowp[1024 + fg * 8];
    bf16x8 ql1 = *(const bf16x8*)&qrowp[1024 + 32 + fg * 8];

    f32x4 o[4];
    float mrow[4], lrow[4];
#pragma unroll
    for (int j = 0; j < 4; ++j) o[j] = (f32x4){0.f, 0.f, 0.f, 0.f};
#pragma unroll
    for (int r = 0; r < 4; ++r) { mrow[r] = -1e30f; lrow[r] = 0.f; }

    const int kend = q0 + 64;
    for (int k0 = 0; k0 < kend; k0 += 32) {
        f32x4 sc2[2];
#pragma unroll
        for (int t = 0; t < 2; ++t) {
            int kb = k0 + t * 16;
            const u16* krowp = K2 + (size_t)(b * SEQ + kb + fr) * 2048 + h * DK;
            bf16x8 kh0 = *(const bf16x8*)&krowp[fg * 8];
            bf16x8 kh1 = *(const bf16x8*)&krowp[32 + fg * 8];
            bf16x8 kl0 = *(const bf16x8*)&krowp[1024 + fg * 8];
            bf16x8 kl1 = *(const bf16x8*)&krowp[1024 + 32 + fg * 8];
            f32x4 a = (f32x4){0.f, 0.f, 0.f, 0.f};
            a = __builtin_amdgcn_mfma_f32_16x16x32_bf16(qh0, kh0, a, 0, 0, 0);
            a = __builtin_amdgcn_mfma_f32_16x16x32_bf16(qh1, kh1, a, 0, 0, 0);
            a = __builtin_amdgcn_mfma_f32_16x16x32_bf16(ql0, kh0, a, 0, 0, 0);
            a = __builtin_amdgcn_mfma_f32_16x16x32_bf16(ql1, kh1, a, 0, 0, 0);
            a = __builtin_amdgcn_mfma_f32_16x16x32_bf16(qh0, kl0, a, 0, 0, 0);
            a = __builtin_amdgcn_mfma_f32_16x16x32_bf16(qh1, kl1, a, 0, 0, 0);
            sc2[t] = a;
        }
#pragma unroll
        for (int r = 0; r < 4; ++r) {
            int qrow = qbase + fg * 4 + r;
            float v0 = (k0 + fr      <= qrow) ? sc2[0][r] * 0.125f : -1e30f;
            float v1 = (k0 + 16 + fr <= qrow) ? sc2[1][r] * 0.125f : -1e30f;
            float mx = fmaxf(v0, v1);
            mx = fmaxf(mx, __shfl_xor(mx, 1));
            mx = fmaxf(mx, __shfl_xor(mx, 2));
            mx = fmaxf(mx, __shfl_xor(mx, 4));
            mx = fmaxf(mx, __shfl_xor(mx, 8));
            float mnew = fmaxf(mrow[r], mx);
            float sc = __expf(mrow[r] - mnew);
            u16 p0b = f2bf(__expf(v0 - mnew));
            u16 p1b = f2bf(__expf(v1 - mnew));
            float rs = bf2f(p0b) + bf2f(p1b);
            rs += __shfl_xor(rs, 1);
            rs += __shfl_xor(rs, 2);
            rs += __shfl_xor(rs, 4);
            rs += __shfl_xor(rs, 8);
            lrow[r] = lrow[r] * sc + rs;
            mrow[r] = mnew;
            // FIX: rescale only THIS row's accumulator component (was broadcast to all 4)
#pragma unroll
            for (int j = 0; j < 4; ++j) o[j][r] *= sc;
            Plds[w][fg * 4 + r][fr]      = p0b;
            Plds[w][fg * 4 + r][16 + fr] = p1b;
        }
        bf16x8 pf = *(const bf16x8*)&Plds[w][fr][fg * 8];
#pragma unroll
        for (int j = 0; j < 4; ++j) {
            const u16* vrowp = &Vt[(size_t)(h * DK + j * 16 + fr) * NROWS + b * SEQ + k0 + fg * 8];
            bf16x8 vf = *(const bf16x8*)vrowp;
            o[j] = __builtin_amdgcn_mfma_f32_16x16x32_bf16(pf, vf, o[j], 0, 0, 0);
        }
    }

#pragma unroll
    for (int r = 0; r < 4; ++r) {
        int qrow = qbase + fg * 4 + r;
        float inv = 1.0f / lrow[r];
        size_t rb = (size_t)(b * SEQ + qrow) * 2048;
#pragma unroll
        for (int j = 0; j < 4; ++j) {
            int col = h * DK + j * 16 + fr;
            float m = o[j][r] * inv;
            u16 mh = f2bf(m);
            u16 ml = f2bf(m - bf2f(mh));
            M2[rb + col]        = mh;
            M2[rb + 1024 + col] = ml;
        }
    }
}

extern "C" void kernel_launch(void* const* d_in, const int* in_sizes, int n_in,
                              void* d_out, int out_size, void* d_ws, size_t ws_size,
                              hipStream_t stream) {
    const float* x   = (const float*)d_in[0];
    const int*   pos = (const int*)d_in[1];
    const float* wq  = (const float*)d_in[2];
    const float* wk  = (const float*)d_in[3];
    const float* wv  = (const float*)d_in[4];
    const float* wo  = (const float*)d_in[5];
    float* out = (float*)d_out;

    char* ws = (char*)d_ws;
    u16* x2  = (u16*)(ws);                    // 16 MB [4096][2048]
    u16* wq2 = (u16*)(ws + (16ull << 20));    //  4 MB [1024][2048]
    u16* wk2 = (u16*)(ws + (20ull << 20));
    u16* wv2 = (u16*)(ws + (24ull << 20));
    u16* wo2 = (u16*)(ws + (28ull << 20));
    u16* Q2  = (u16*)(ws + (32ull << 20));    // 16 MB [4096][2048]
    u16* K2  = (u16*)(ws + (48ull << 20));    // 16 MB (contiguous after Q2)
    u16* Vt  = (u16*)(ws + (64ull << 20));    //  8 MB [1024][4096]
    u16* M2  = (u16*)(ws);                    // 16 MB, reuses x2 (dead after V GEMM)

    // 1) split-convert inputs
    cvt_split<<<4096, 256, 0, stream>>>(x,  x2,  NROWS * 256);
    cvt_split<<<1024, 256, 0, stream>>>(wq, wq2, D_MODEL * 256);
    cvt_split<<<1024, 256, 0, stream>>>(wk, wk2, D_MODEL * 256);
    cvt_split<<<1024, 256, 0, stream>>>(wv, wv2, D_MODEL * 256);
    cvt_split<<<1024, 256, 0, stream>>>(wo, wo2, D_MODEL * 256);

    // 2) QKV projections (f32-accurate via 3-product split)
    dim3 ggrid(NROWS / 128, D_MODEL / 128);
    gemm_split<0><<<ggrid, 256, 0, stream>>>(x2, wq2, Q2, NROWS);
    gemm_split<0><<<ggrid, 256, 0, stream>>>(x2, wk2, K2, NROWS);
    gemm_split<1><<<ggrid, 256, 0, stream>>>(x2, wv2, Vt, NROWS);

    // 3) RoPE in place on Q2||K2 (lossless hi+lo reconstruct, rotate in f32, re-split)
    rope_inplace<<<16384, 256, 0, stream>>>(Q2, pos);

    // 4) causal flash attention -> split merged context
    attn_kernel<<<dim3(SEQ / 64, NHEADS, BATCH), 256, 0, stream>>>(Q2, K2, Vt, M2);

    // 5) output projection (split x split, f32 epilogue)
    gemm_split<2><<<ggrid, 256, 0, stream>>>(M2, wo2, out, NROWS);
}

// Round 4
// 411.671 us; speedup vs baseline: 1.2993x; 1.2993x over previous
//
#include <hip/hip_runtime.h>

#define D_MODEL 1024
#define SEQ     2048
#define BATCH   2
#define NHEADS  16
#define DK      64
#define NROWS   (BATCH*SEQ)   // 4096

typedef unsigned short u16;
typedef __bf16 bf16x8 __attribute__((ext_vector_type(8)));
typedef float  f32x4  __attribute__((ext_vector_type(4)));

__device__ __forceinline__ u16 f2bf(float f) {
    union { float f; unsigned u; } v; v.f = f;
    unsigned u = v.u;
    u += 0x7fffu + ((u >> 16) & 1);
    return (u16)(u >> 16);
}
__device__ __forceinline__ float bf2f(u16 h) {
    union { unsigned u; float f; } v; v.u = ((unsigned)h) << 16;
    return v.f;
}

// ---------- f32 [R][1024] -> bf16 split [R][2048] = [hi(1024) | lo(1024)] ----------
__global__ void cvt_split(const float* __restrict__ src, u16* __restrict__ dst, int total4) {
    int i = blockIdx.x * blockDim.x + threadIdx.x;
    if (i >= total4) return;
    int row = i >> 8;
    int c   = (i & 255) * 4;
    float4 v = *(const float4*)(src + (size_t)row * 1024 + c);
    u16 h0 = f2bf(v.x), h1 = f2bf(v.y), h2 = f2bf(v.z), h3 = f2bf(v.w);
    u16 l0 = f2bf(v.x - bf2f(h0)), l1 = f2bf(v.y - bf2f(h1));
    u16 l2 = f2bf(v.z - bf2f(h2)), l3 = f2bf(v.w - bf2f(h3));
    size_t b = (size_t)row * 2048;
    uint2 ph; ph.x = h0 | ((unsigned)h1 << 16); ph.y = h2 | ((unsigned)h3 << 16);
    uint2 pl; pl.x = l0 | ((unsigned)l1 << 16); pl.y = l2 | ((unsigned)l3 << 16);
    *(uint2*)&dst[b + c]        = ph;
    *(uint2*)&dst[b + 1024 + c] = pl;
}

// 4 weight matrices in one launch (each 1024x1024, split-convert)
__global__ void cvt_split4(const float* __restrict__ s0, const float* __restrict__ s1,
                           const float* __restrict__ s2, const float* __restrict__ s3,
                           u16* __restrict__ dst) {
    int i = blockIdx.x * blockDim.x + threadIdx.x;     // 4 * 262144 chunks
    int wsel = i >> 18;
    int j = i & 262143;
    const float* src = wsel == 0 ? s0 : wsel == 1 ? s1 : wsel == 2 ? s2 : s3;
    int row = j >> 8;
    int c   = (j & 255) * 4;
    float4 v = *(const float4*)(src + (size_t)row * 1024 + c);
    u16 h0 = f2bf(v.x), h1 = f2bf(v.y), h2 = f2bf(v.z), h3 = f2bf(v.w);
    u16 l0 = f2bf(v.x - bf2f(h0)), l1 = f2bf(v.y - bf2f(h1));
    u16 l2 = f2bf(v.z - bf2f(h2)), l3 = f2bf(v.w - bf2f(h3));
    size_t b = (size_t)wsel * (2048 * 1024) + (size_t)row * 2048;
    uint2 ph; ph.x = h0 | ((unsigned)h1 << 16); ph.y = h2 | ((unsigned)h3 << 16);
    uint2 pl; pl.x = l0 | ((unsigned)l1 << 16); pl.y = l2 | ((unsigned)l3 << 16);
    *(uint2*)&dst[b + c]        = ph;
    *(uint2*)&dst[b + 1024 + c] = pl;
}

// ---------- split x split GEMM (3 MFMA), C plain bf16 ----------
// MODE 0: C bf16 [M][1024] row-major; MODE 1: C bf16 [1024][M] transposed.
template<int MODE>
__global__ __launch_bounds__(256) void gemm3(
    const u16* __restrict__ A2, const u16* __restrict__ B2, u16* __restrict__ Cout, int M)
{
    __shared__ __align__(16) u16 Ash[128 * 40];
    __shared__ __align__(16) u16 Asl[128 * 40];
    __shared__ __align__(16) u16 Bsh[128 * 40];
    __shared__ __align__(16) u16 Bsl[128 * 40];

    const int m0 = blockIdx.x * 128;
    const int n0 = blockIdx.y * 128;
    const int tid = threadIdx.x;
    const int lane = tid & 63;
    const int wid  = tid >> 6;
    const int wr = wid >> 1, wc = wid & 1;
    const int fr = lane & 15;
    const int fk = (lane >> 4) * 8;

    f32x4 acc[4][4];
#pragma unroll
    for (int i = 0; i < 4; ++i)
#pragma unroll
        for (int j = 0; j < 4; ++j) acc[i][j] = (f32x4){0.f, 0.f, 0.f, 0.f};

    for (int k0 = 0; k0 < 1024; k0 += 32) {
        __syncthreads();
#pragma unroll
        for (int s = 0; s < 2; ++s) {
            int c   = tid + s * 256;
            int row = c >> 2;
            int cb  = (c & 3) * 8;
            const u16* ap = A2 + (size_t)(m0 + row) * 2048 + k0 + cb;
            *(uint4*)&Ash[row * 40 + cb] = *(const uint4*)ap;
            *(uint4*)&Asl[row * 40 + cb] = *(const uint4*)(ap + 1024);
            const u16* bp = B2 + (size_t)(n0 + row) * 2048 + k0 + cb;
            *(uint4*)&Bsh[row * 40 + cb] = *(const uint4*)bp;
            *(uint4*)&Bsl[row * 40 + cb] = *(const uint4*)(bp + 1024);
        }
        __syncthreads();

        bf16x8 ah[4], al[4], bh[4], bl[4];
#pragma unroll
        for (int i = 0; i < 4; ++i) {
            ah[i] = *(const bf16x8*)&Ash[(wr * 64 + i * 16 + fr) * 40 + fk];
            al[i] = *(const bf16x8*)&Asl[(wr * 64 + i * 16 + fr) * 40 + fk];
        }
#pragma unroll
        for (int j = 0; j < 4; ++j) {
            bh[j] = *(const bf16x8*)&Bsh[(wc * 64 + j * 16 + fr) * 40 + fk];
            bl[j] = *(const bf16x8*)&Bsl[(wc * 64 + j * 16 + fr) * 40 + fk];
        }
#pragma unroll
        for (int i = 0; i < 4; ++i)
#pragma unroll
            for (int j = 0; j < 4; ++j) {
                acc[i][j] = __builtin_amdgcn_mfma_f32_16x16x32_bf16(ah[i], bh[j], acc[i][j], 0, 0, 0);
                acc[i][j] = __builtin_amdgcn_mfma_f32_16x16x32_bf16(al[i], bh[j], acc[i][j], 0, 0, 0);
                acc[i][j] = __builtin_amdgcn_mfma_f32_16x16x32_bf16(ah[i], bl[j], acc[i][j], 0, 0, 0);
            }
    }

    const int r0 = (lane >> 4) * 4;
#pragma unroll
    for (int i = 0; i < 4; ++i) {
        int row = m0 + wr * 64 + i * 16 + r0;
#pragma unroll
        for (int j = 0; j < 4; ++j) {
            int col = n0 + wc * 64 + j * 16 + fr;
#pragma unroll
            for (int r = 0; r < 4; ++r) {
                float v = acc[i][j][r];
                if (MODE == 0) Cout[(size_t)(row + r) * 1024 + col] = f2bf(v);
                else           Cout[(size_t)col * M + (row + r)]   = f2bf(v);
            }
        }
    }
}

// ---------- plain A x split B GEMM (2 MFMA), C f32 ----------
__global__ __launch_bounds__(256) void gemm_out(
    const u16* __restrict__ A, const u16* __restrict__ B2, float* __restrict__ Cout)
{
    __shared__ __align__(16) u16 Ash[128 * 40];
    __shared__ __align__(16) u16 Bsh[128 * 40];
    __shared__ __align__(16) u16 Bsl[128 * 40];

    const int m0 = blockIdx.x * 128;
    const int n0 = blockIdx.y * 128;
    const int tid = threadIdx.x;
    const int lane = tid & 63;
    const int wid  = tid >> 6;
    const int wr = wid >> 1, wc = wid & 1;
    const int fr = lane & 15;
    const int fk = (lane >> 4) * 8;

    f32x4 acc[4][4];
#pragma unroll
    for (int i = 0; i < 4; ++i)
#pragma unroll
        for (int j = 0; j < 4; ++j) acc[i][j] = (f32x4){0.f, 0.f, 0.f, 0.f};

    for (int k0 = 0; k0 < 1024; k0 += 32) {
        __syncthreads();
#pragma unroll
        for (int s = 0; s < 2; ++s) {
            int c   = tid + s * 256;
            int row = c >> 2;
            int cb  = (c & 3) * 8;
            *(uint4*)&Ash[row * 40 + cb] = *(const uint4*)(A + (size_t)(m0 + row) * 1024 + k0 + cb);
            const u16* bp = B2 + (size_t)(n0 + row) * 2048 + k0 + cb;
            *(uint4*)&Bsh[row * 40 + cb] = *(const uint4*)bp;
            *(uint4*)&Bsl[row * 40 + cb] = *(const uint4*)(bp + 1024);
        }
        __syncthreads();

        bf16x8 ah[4], bh[4], bl[4];
#pragma unroll
        for (int i = 0; i < 4; ++i)
            ah[i] = *(const bf16x8*)&Ash[(wr * 64 + i * 16 + fr) * 40 + fk];
#pragma unroll
        for (int j = 0; j < 4; ++j) {
            bh[j] = *(const bf16x8*)&Bsh[(wc * 64 + j * 16 + fr) * 40 + fk];
            bl[j] = *(const bf16x8*)&Bsl[(wc * 64 + j * 16 + fr) * 40 + fk];
        }
#pragma unroll
        for (int i = 0; i < 4; ++i)
#pragma unroll
            for (int j = 0; j < 4; ++j) {
                acc[i][j] = __builtin_amdgcn_mfma_f32_16x16x32_bf16(ah[i], bh[j], acc[i][j], 0, 0, 0);
                acc[i][j] = __builtin_amdgcn_mfma_f32_16x16x32_bf16(ah[i], bl[j], acc[i][j], 0, 0, 0);
            }
    }

    const int r0 = (lane >> 4) * 4;
#pragma unroll
    for (int i = 0; i < 4; ++i) {
        int row = m0 + wr * 64 + i * 16 + r0;
#pragma unroll
        for (int j = 0; j < 4; ++j) {
            int col = n0 + wc * 64 + j * 16 + fr;
#pragma unroll
            for (int r = 0; r < 4; ++r)
                Cout[(size_t)(row + r) * 1024 + col] = acc[i][j][r];
        }
    }
}

// ---------- RoPE in place on plain Q||K [8192][1024] ----------
__global__ void rope_plain(u16* __restrict__ qk, const int* __restrict__ pos) {
    int i = blockIdx.x * blockDim.x + threadIdx.x;   // 8192 rows * 512 pairs
    int p = i & 511;
    int n = i >> 9;
    int s = n & 2047;
    int k = p & 31;
    int h = p >> 5;
    size_t base = (size_t)n * 1024 + h * DK + 2 * k;
    unsigned v = *(const unsigned*)&qk[base];
    float x0 = bf2f((u16)(v & 0xffff));
    float x1 = bf2f((u16)(v >> 16));
    float ang = (float)pos[s] * expf((float)k * -0.28782313662425575f);  // theta^(-k/32)
    float c = cosf(ang), sn = sinf(ang);
    float y0 = x0 * c - x1 * sn;
    float y1 = x1 * c + x0 * sn;
    *(unsigned*)&qk[base] = (unsigned)f2bf(y0) | ((unsigned)f2bf(y1) << 16);
}

// ---------- causal flash attention v2: plain bf16, KVBLK=64, K-prefetch ----------
__global__ __launch_bounds__(256) void attn_v2(
    const u16* __restrict__ Qp, const u16* __restrict__ Kp,
    const u16* __restrict__ Vt, u16* __restrict__ Mb)
{
    const int qt = gridDim.x - 1 - blockIdx.x;   // longest blocks dispatch first
    const int h  = blockIdx.y;
    const int b  = blockIdx.z;
    const int lane = threadIdx.x & 63;
    const int w    = threadIdx.x >> 6;
    const int q0 = qt * 64;
    const int qbase = q0 + w * 16;
    const int fr = lane & 15;
    const int fg = lane >> 4;
    const int bS = b * SEQ;
    const int hd = h * DK;

    __shared__ __align__(16) u16 Plds[4][16][72];

    const u16* qrow = Qp + (size_t)(bS + qbase + fr) * 1024 + hd;
    bf16x8 qf0 = *(const bf16x8*)(qrow + fg * 8);
    bf16x8 qf1 = *(const bf16x8*)(qrow + 32 + fg * 8);

    f32x4 o[4];
    float mrow[4], lrow[4];
#pragma unroll
    for (int j = 0; j < 4; ++j) o[j] = (f32x4){0.f, 0.f, 0.f, 0.f};
#pragma unroll
    for (int r = 0; r < 4; ++r) { mrow[r] = -1e30f; lrow[r] = 0.f; }

    const int nt = qt + 1;

#define LDK(BUF, KT) do { \
    int kb_ = (KT) * 64; \
    _Pragma("unroll") \
    for (int t = 0; t < 4; ++t) { \
        const u16* kp_ = Kp + (size_t)(bS + kb_ + t * 16 + fr) * 1024 + hd; \
        BUF[t][0] = *(const bf16x8*)(kp_ + fg * 8); \
        BUF[t][1] = *(const bf16x8*)(kp_ + 32 + fg * 8); \
    } \
} while (0)

#define PROCESS(BUF, KT) do { \
    const int k0_ = (KT) * 64; \
    const bool diag_ = ((KT) == nt - 1); \
    bf16x8 vf_[4][2]; \
    _Pragma("unroll") \
    for (int j = 0; j < 4; ++j) { \
        const u16* vp_ = Vt + (size_t)(hd + j * 16 + fr) * NROWS + bS + k0_; \
        vf_[j][0] = *(const bf16x8*)(vp_ + fg * 8); \
        vf_[j][1] = *(const bf16x8*)(vp_ + 32 + fg * 8); \
    } \
    f32x4 s_[4]; \
    _Pragma("unroll") \
    for (int t = 0; t < 4; ++t) { \
        f32x4 a_ = (f32x4){0.f, 0.f, 0.f, 0.f}; \
        a_ = __builtin_amdgcn_mfma_f32_16x16x32_bf16(qf0, BUF[t][0], a_, 0, 0, 0); \
        a_ = __builtin_amdgcn_mfma_f32_16x16x32_bf16(qf1, BUF[t][1], a_, 0, 0, 0); \
        s_[t] = a_; \
    } \
    _Pragma("unroll") \
    for (int r = 0; r < 4; ++r) { \
        int qr_ = qbase + fg * 4 + r; \
        float v0_ = s_[0][r] * 0.125f, v1_ = s_[1][r] * 0.125f; \
        float v2_ = s_[2][r] * 0.125f, v3_ = s_[3][r] * 0.125f; \
        if (diag_) { \
            if (k0_      + fr > qr_) v0_ = -1e30f; \
            if (k0_ + 16 + fr > qr_) v1_ = -1e30f; \
            if (k0_ + 32 + fr > qr_) v2_ = -1e30f; \
            if (k0_ + 48 + fr > qr_) v3_ = -1e30f; \
        } \
        float mx_ = fmaxf(fmaxf(v0_, v1_), fmaxf(v2_, v3_)); \
        mx_ = fmaxf(mx_, __shfl_xor(mx_, 1)); \
        mx_ = fmaxf(mx_, __shfl_xor(mx_, 2)); \
        mx_ = fmaxf(mx_, __shfl_xor(mx_, 4)); \
        mx_ = fmaxf(mx_, __shfl_xor(mx_, 8)); \
        float mnew_ = fmaxf(mrow[r], mx_); \
        float sc_ = __expf(mrow[r] - mnew_); \
        float p0_ = __expf(v0_ - mnew_), p1_ = __expf(v1_ - mnew_); \
        float p2_ = __expf(v2_ - mnew_), p3_ = __expf(v3_ - mnew_); \
        float rs_ = (p0_ + p1_) + (p2_ + p3_); \
        rs_ += __shfl_xor(rs_, 1); \
        rs_ += __shfl_xor(rs_, 2); \
        rs_ += __shfl_xor(rs_, 4); \
        rs_ += __shfl_xor(rs_, 8); \
        lrow[r] = lrow[r] * sc_ + rs_; \
        mrow[r] = mnew_; \
        o[0][r] *= sc_; o[1][r] *= sc_; o[2][r] *= sc_; o[3][r] *= sc_; \
        Plds[w][fg * 4 + r][     fr] = f2bf(p0_); \
        Plds[w][fg * 4 + r][16 + fr] = f2bf(p1_); \
        Plds[w][fg * 4 + r][32 + fr] = f2bf(p2_); \
        Plds[w][fg * 4 + r][48 + fr] = f2bf(p3_); \
    } \
    bf16x8 pf0_ = *(const bf16x8*)&Plds[w][fr][fg * 8]; \
    bf16x8 pf1_ = *(const bf16x8*)&Plds[w][fr][32 + fg * 8]; \
    _Pragma("unroll") \
    for (int j = 0; j < 4; ++j) { \
        o[j] = __builtin_amdgcn_mfma_f32_16x16x32_bf16(pf0_, vf_[j][0], o[j], 0, 0, 0); \
        o[j] = __builtin_amdgcn_mfma_f32_16x16x32_bf16(pf1_, vf_[j][1], o[j], 0, 0, 0); \
    } \
} while (0)

    bf16x8 kA[4][2], kB[4][2];
    int kt = 0;
    LDK(kA, 0);
    while (true) {
        LDK(kB, (kt + 1 < nt) ? kt + 1 : nt - 1);
        PROCESS(kA, kt);
        ++kt; if (kt >= nt) break;
        LDK(kA, (kt + 1 < nt) ? kt + 1 : nt - 1);
        PROCESS(kB, kt);
        ++kt; if (kt >= nt) break;
    }
#undef LDK
#undef PROCESS

#pragma unroll
    for (int r = 0; r < 4; ++r) {
        int qrow = qbase + fg * 4 + r;
        float inv = 1.0f / lrow[r];
#pragma unroll
        for (int j = 0; j < 4; ++j)
            Mb[(size_t)(bS + qrow) * 1024 + hd + j * 16 + fr] = f2bf(o[j][r] * inv);
    }
}

extern "C" void kernel_launch(void* const* d_in, const int* in_sizes, int n_in,
                              void* d_out, int out_size, void* d_ws, size_t ws_size,
                              hipStream_t stream) {
    const float* x   = (const float*)d_in[0];
    const int*   pos = (const int*)d_in[1];
    const float* wq  = (const float*)d_in[2];
    const float* wk  = (const float*)d_in[3];
    const float* wv  = (const float*)d_in[4];
    const float* wo  = (const float*)d_in[5];
    float* out = (float*)d_out;

    char* ws = (char*)d_ws;
    u16* x2  = (u16*)(ws);                    // 16 MB split [4096][2048]
    u16* w2  = (u16*)(ws + (16ull << 20));    // 16 MB: wq2|wk2|wv2|wo2 split, 4 MB each
    u16* wq2 = w2;
    u16* wk2 = w2 + 2048 * 1024;
    u16* wv2 = w2 + 2 * 2048 * 1024;
    u16* wo2 = w2 + 3 * 2048 * 1024;
    u16* Qp  = (u16*)(ws + (32ull << 20));    //  8 MB plain [4096][1024]
    u16* Kp  = (u16*)(ws + (40ull << 20));    //  8 MB plain (contiguous after Qp)
    u16* Vt  = (u16*)(ws + (48ull << 20));    //  8 MB plain transposed [1024][4096]
    u16* Mb  = (u16*)(ws + (56ull << 20));    //  8 MB plain [4096][1024]

    // 1) convert inputs (x split; 4 weights split, fused launch)
    cvt_split<<<4096, 256, 0, stream>>>(x, x2, NROWS * 256);
    cvt_split4<<<4096, 256, 0, stream>>>(wq, wk, wv, wo, w2);

    // 2) QKV projections (split x split, 3-MFMA; plain bf16 outputs)
    dim3 ggrid(NROWS / 128, D_MODEL / 128);
    gemm3<0><<<ggrid, 256, 0, stream>>>(x2, wq2, Qp, NROWS);
    gemm3<0><<<ggrid, 256, 0, stream>>>(x2, wk2, Kp, NROWS);
    gemm3<1><<<ggrid, 256, 0, stream>>>(x2, wv2, Vt, NROWS);

    // 3) RoPE in place on plain Qp||Kp
    rope_plain<<<16384, 256, 0, stream>>>(Qp, pos);

    // 4) causal flash attention v2
    attn_v2<<<dim3(SEQ / 64, NHEADS, BATCH), 256, 0, stream>>>(Qp, Kp, Vt, Mb);

    // 5) output projection (plain M x split wo, f32 out)
    gemm_out<<<ggrid, 256, 0, stream>>>(Mb, wo2, out);
}

// Round 5
// 384.817 us; speedup vs baseline: 1.3899x; 1.0698x over previous
//
#include <hip/hip_runtime.h>

#define D_MODEL 1024
#define SEQ     2048
#define BATCH   2
#define NHEADS  16
#define DK      64
#define NROWS   (BATCH*SEQ)   // 4096

typedef unsigned short u16;
typedef __bf16 bf16x8 __attribute__((ext_vector_type(8)));
typedef float  f32x4  __attribute__((ext_vector_type(4)));

__device__ __forceinline__ u16 f2bf(float f) {
    union { float f; unsigned u; } v; v.f = f;
    unsigned u = v.u;
    u += 0x7fffu + ((u >> 16) & 1);
    return (u16)(u >> 16);
}
__device__ __forceinline__ float bf2f(u16 h) {
    union { unsigned u; float f; } v; v.u = ((unsigned)h) << 16;
    return v.f;
}

// ---------- f32 [R][1024] -> bf16 split [R][2048] = [hi(1024) | lo(1024)] ----------
__global__ void cvt_split(const float* __restrict__ src, u16* __restrict__ dst, int total4) {
    int i = blockIdx.x * blockDim.x + threadIdx.x;
    if (i >= total4) return;
    int row = i >> 8;
    int c   = (i & 255) * 4;
    float4 v = *(const float4*)(src + (size_t)row * 1024 + c);
    u16 h0 = f2bf(v.x), h1 = f2bf(v.y), h2 = f2bf(v.z), h3 = f2bf(v.w);
    u16 l0 = f2bf(v.x - bf2f(h0)), l1 = f2bf(v.y - bf2f(h1));
    u16 l2 = f2bf(v.z - bf2f(h2)), l3 = f2bf(v.w - bf2f(h3));
    size_t b = (size_t)row * 2048;
    uint2 ph; ph.x = h0 | ((unsigned)h1 << 16); ph.y = h2 | ((unsigned)h3 << 16);
    uint2 pl; pl.x = l0 | ((unsigned)l1 << 16); pl.y = l2 | ((unsigned)l3 << 16);
    *(uint2*)&dst[b + c]        = ph;
    *(uint2*)&dst[b + 1024 + c] = pl;
}

// 4 weight matrices in one launch (each 1024x1024, split-convert)
__global__ void cvt_split4(const float* __restrict__ s0, const float* __restrict__ s1,
                           const float* __restrict__ s2, const float* __restrict__ s3,
                           u16* __restrict__ dst) {
    int i = blockIdx.x * blockDim.x + threadIdx.x;
    int wsel = i >> 18;
    int j = i & 262143;
    const float* src = wsel == 0 ? s0 : wsel == 1 ? s1 : wsel == 2 ? s2 : s3;
    int row = j >> 8;
    int c   = (j & 255) * 4;
    float4 v = *(const float4*)(src + (size_t)row * 1024 + c);
    u16 h0 = f2bf(v.x), h1 = f2bf(v.y), h2 = f2bf(v.z), h3 = f2bf(v.w);
    u16 l0 = f2bf(v.x - bf2f(h0)), l1 = f2bf(v.y - bf2f(h1));
    u16 l2 = f2bf(v.z - bf2f(h2)), l3 = f2bf(v.w - bf2f(h3));
    size_t b = (size_t)wsel * (2048 * 1024) + (size_t)row * 2048;
    uint2 ph; ph.x = h0 | ((unsigned)h1 << 16); ph.y = h2 | ((unsigned)h3 << 16);
    uint2 pl; pl.x = l0 | ((unsigned)l1 << 16); pl.y = l2 | ((unsigned)l3 << 16);
    *(uint2*)&dst[b + c]        = ph;
    *(uint2*)&dst[b + 1024 + c] = pl;
}

// ---------- split x split GEMM (3 MFMA), C plain bf16 ----------
template<int MODE>
__global__ __launch_bounds__(256) void gemm3(
    const u16* __restrict__ A2, const u16* __restrict__ B2, u16* __restrict__ Cout, int M)
{
    __shared__ __align__(16) u16 Ash[128 * 40];
    __shared__ __align__(16) u16 Asl[128 * 40];
    __shared__ __align__(16) u16 Bsh[128 * 40];
    __shared__ __align__(16) u16 Bsl[128 * 40];

    const int m0 = blockIdx.x * 128;
    const int n0 = blockIdx.y * 128;
    const int tid = threadIdx.x;
    const int lane = tid & 63;
    const int wid  = tid >> 6;
    const int wr = wid >> 1, wc = wid & 1;
    const int fr = lane & 15;
    const int fk = (lane >> 4) * 8;

    f32x4 acc[4][4];
#pragma unroll
    for (int i = 0; i < 4; ++i)
#pragma unroll
        for (int j = 0; j < 4; ++j) acc[i][j] = (f32x4){0.f, 0.f, 0.f, 0.f};

    for (int k0 = 0; k0 < 1024; k0 += 32) {
        __syncthreads();
#pragma unroll
        for (int s = 0; s < 2; ++s) {
            int c   = tid + s * 256;
            int row = c >> 2;
            int cb  = (c & 3) * 8;
            const u16* ap = A2 + (size_t)(m0 + row) * 2048 + k0 + cb;
            *(uint4*)&Ash[row * 40 + cb] = *(const uint4*)ap;
            *(uint4*)&Asl[row * 40 + cb] = *(const uint4*)(ap + 1024);
            const u16* bp = B2 + (size_t)(n0 + row) * 2048 + k0 + cb;
            *(uint4*)&Bsh[row * 40 + cb] = *(const uint4*)bp;
            *(uint4*)&Bsl[row * 40 + cb] = *(const uint4*)(bp + 1024);
        }
        __syncthreads();

        bf16x8 ah[4], al[4], bh[4], bl[4];
#pragma unroll
        for (int i = 0; i < 4; ++i) {
            ah[i] = *(const bf16x8*)&Ash[(wr * 64 + i * 16 + fr) * 40 + fk];
            al[i] = *(const bf16x8*)&Asl[(wr * 64 + i * 16 + fr) * 40 + fk];
        }
#pragma unroll
        for (int j = 0; j < 4; ++j) {
            bh[j] = *(const bf16x8*)&Bsh[(wc * 64 + j * 16 + fr) * 40 + fk];
            bl[j] = *(const bf16x8*)&Bsl[(wc * 64 + j * 16 + fr) * 40 + fk];
        }
#pragma unroll
        for (int i = 0; i < 4; ++i)
#pragma unroll
            for (int j = 0; j < 4; ++j) {
                acc[i][j] = __builtin_amdgcn_mfma_f32_16x16x32_bf16(ah[i], bh[j], acc[i][j], 0, 0, 0);
                acc[i][j] = __builtin_amdgcn_mfma_f32_16x16x32_bf16(al[i], bh[j], acc[i][j], 0, 0, 0);
                acc[i][j] = __builtin_amdgcn_mfma_f32_16x16x32_bf16(ah[i], bl[j], acc[i][j], 0, 0, 0);
            }
    }

    const int r0 = (lane >> 4) * 4;
#pragma unroll
    for (int i = 0; i < 4; ++i) {
        int row = m0 + wr * 64 + i * 16 + r0;
#pragma unroll
        for (int j = 0; j < 4; ++j) {
            int col = n0 + wc * 64 + j * 16 + fr;
#pragma unroll
            for (int r = 0; r < 4; ++r) {
                float v = acc[i][j][r];
                if (MODE == 0) Cout[(size_t)(row + r) * 1024 + col] = f2bf(v);
                else           Cout[(size_t)col * M + (row + r)]   = f2bf(v);
            }
        }
    }
}

// ---------- plain A x split B GEMM (2 MFMA), C f32 ----------
__global__ __launch_bounds__(256) void gemm_out(
    const u16* __restrict__ A, const u16* __restrict__ B2, float* __restrict__ Cout)
{
    __shared__ __align__(16) u16 Ash[128 * 40];
    __shared__ __align__(16) u16 Bsh[128 * 40];
    __shared__ __align__(16) u16 Bsl[128 * 40];

    const int m0 = blockIdx.x * 128;
    const int n0 = blockIdx.y * 128;
    const int tid = threadIdx.x;
    const int lane = tid & 63;
    const int wid  = tid >> 6;
    const int wr = wid >> 1, wc = wid & 1;
    const int fr = lane & 15;
    const int fk = (lane >> 4) * 8;

    f32x4 acc[4][4];
#pragma unroll
    for (int i = 0; i < 4; ++i)
#pragma unroll
        for (int j = 0; j < 4; ++j) acc[i][j] = (f32x4){0.f, 0.f, 0.f, 0.f};

    for (int k0 = 0; k0 < 1024; k0 += 32) {
        __syncthreads();
#pragma unroll
        for (int s = 0; s < 2; ++s) {
            int c   = tid + s * 256;
            int row = c >> 2;
            int cb  = (c & 3) * 8;
            *(uint4*)&Ash[row * 40 + cb] = *(const uint4*)(A + (size_t)(m0 + row) * 1024 + k0 + cb);
            const u16* bp = B2 + (size_t)(n0 + row) * 2048 + k0 + cb;
            *(uint4*)&Bsh[row * 40 + cb] = *(const uint4*)bp;
            *(uint4*)&Bsl[row * 40 + cb] = *(const uint4*)(bp + 1024);
        }
        __syncthreads();

        bf16x8 ah[4], bh[4], bl[4];
#pragma unroll
        for (int i = 0; i < 4; ++i)
            ah[i] = *(const bf16x8*)&Ash[(wr * 64 + i * 16 + fr) * 40 + fk];
#pragma unroll
        for (int j = 0; j < 4; ++j) {
            bh[j] = *(const bf16x8*)&Bsh[(wc * 64 + j * 16 + fr) * 40 + fk];
            bl[j] = *(const bf16x8*)&Bsl[(wc * 64 + j * 16 + fr) * 40 + fk];
        }
#pragma unroll
        for (int i = 0; i < 4; ++i)
#pragma unroll
            for (int j = 0; j < 4; ++j) {
                acc[i][j] = __builtin_amdgcn_mfma_f32_16x16x32_bf16(ah[i], bh[j], acc[i][j], 0, 0, 0);
                acc[i][j] = __builtin_amdgcn_mfma_f32_16x16x32_bf16(ah[i], bl[j], acc[i][j], 0, 0, 0);
            }
    }

    const int r0 = (lane >> 4) * 4;
#pragma unroll
    for (int i = 0; i < 4; ++i) {
        int row = m0 + wr * 64 + i * 16 + r0;
#pragma unroll
        for (int j = 0; j < 4; ++j) {
            int col = n0 + wc * 64 + j * 16 + fr;
#pragma unroll
            for (int r = 0; r < 4; ++r)
                Cout[(size_t)(row + r) * 1024 + col] = acc[i][j][r];
        }
    }
}

// ---------- RoPE in place on plain Q||K [8192][1024] ----------
__global__ void rope_plain(u16* __restrict__ qk, const int* __restrict__ pos) {
    int i = blockIdx.x * blockDim.x + threadIdx.x;
    int p = i & 511;
    int n = i >> 9;
    int s = n & 2047;
    int k = p & 31;
    int h = p >> 5;
    size_t base = (size_t)n * 1024 + h * DK + 2 * k;
    unsigned v = *(const unsigned*)&qk[base];
    float x0 = bf2f((u16)(v & 0xffff));
    float x1 = bf2f((u16)(v >> 16));
    float ang = (float)pos[s] * expf((float)k * -0.28782313662425575f);
    float c = cosf(ang), sn = sinf(ang);
    float y0 = x0 * c - x1 * sn;
    float y1 = x1 * c + x0 * sn;
    *(unsigned*)&qk[base] = (unsigned)f2bf(y0) | ((unsigned)f2bf(y1) << 16);
}

// ---------- causal flash attention v3: split-K (flash-decoding, 2-way) ----------
// Each block: 64 q-rows, half of the key tiles. Writes raw partial O (bf16) + m,l (f32).
__global__ __launch_bounds__(256) void attn_v3(
    const u16* __restrict__ Qp, const u16* __restrict__ Kp, const u16* __restrict__ Vt,
    u16* __restrict__ Op0, u16* __restrict__ Op1, float* __restrict__ mlbuf)
{
    const int xx = blockIdx.x;          // 0..63
    const int qt = 31 - (xx >> 1);      // longest splits dispatch first
    const int s  = xx & 1;
    const int h  = blockIdx.y;
    const int b  = blockIdx.z;
    const int lane = threadIdx.x & 63;
    const int w    = threadIdx.x >> 6;
    const int q0 = qt * 64;
    const int qbase = q0 + w * 16;
    const int fr = lane & 15;
    const int fg = lane >> 4;
    const int bS = b * SEQ;
    const int hd = h * DK;

    const int nt   = qt + 1;
    const int tmid = (nt + 1) >> 1;
    const int t0 = s ? tmid : 0;
    const int t1 = s ? nt : tmid;

    __shared__ __align__(16) u16 Plds[4][16][72];

    const u16* qrow = Qp + (size_t)(bS + qbase + fr) * 1024 + hd;
    bf16x8 qf0 = *(const bf16x8*)(qrow + fg * 8);
    bf16x8 qf1 = *(const bf16x8*)(qrow + 32 + fg * 8);

    f32x4 o[4];
    float mrow[4], lrow[4];
#pragma unroll
    for (int j = 0; j < 4; ++j) o[j] = (f32x4){0.f, 0.f, 0.f, 0.f};
#pragma unroll
    for (int r = 0; r < 4; ++r) { mrow[r] = -1e30f; lrow[r] = 0.f; }

#define LDK(BUF, KT) do { \
    int kb_ = (KT) * 64; \
    _Pragma("unroll") \
    for (int t = 0; t < 4; ++t) { \
        const u16* kp_ = Kp + (size_t)(bS + kb_ + t * 16 + fr) * 1024 + hd; \
        BUF[t][0] = *(const bf16x8*)(kp_ + fg * 8); \
        BUF[t][1] = *(const bf16x8*)(kp_ + 32 + fg * 8); \
    } \
} while (0)

#define PROCESS(BUF, KT) do { \
    const int k0_ = (KT) * 64; \
    const bool diag_ = ((KT) == nt - 1); \
    bf16x8 vf_[4][2]; \
    _Pragma("unroll") \
    for (int j = 0; j < 4; ++j) { \
        const u16* vp_ = Vt + (size_t)(hd + j * 16 + fr) * NROWS + bS + k0_; \
        vf_[j][0] = *(const bf16x8*)(vp_ + fg * 8); \
        vf_[j][1] = *(const bf16x8*)(vp_ + 32 + fg * 8); \
    } \
    f32x4 s_[4]; \
    _Pragma("unroll") \
    for (int t = 0; t < 4; ++t) { \
        f32x4 a_ = (f32x4){0.f, 0.f, 0.f, 0.f}; \
        a_ = __builtin_amdgcn_mfma_f32_16x16x32_bf16(qf0, BUF[t][0], a_, 0, 0, 0); \
        a_ = __builtin_amdgcn_mfma_f32_16x16x32_bf16(qf1, BUF[t][1], a_, 0, 0, 0); \
        s_[t] = a_; \
    } \
    _Pragma("unroll") \
    for (int r = 0; r < 4; ++r) { \
        int qr_ = qbase + fg * 4 + r; \
        float v0_ = s_[0][r] * 0.125f, v1_ = s_[1][r] * 0.125f; \
        float v2_ = s_[2][r] * 0.125f, v3_ = s_[3][r] * 0.125f; \
        if (diag_) { \
            if (k0_      + fr > qr_) v0_ = -1e30f; \
            if (k0_ + 16 + fr > qr_) v1_ = -1e30f; \
            if (k0_ + 32 + fr > qr_) v2_ = -1e30f; \
            if (k0_ + 48 + fr > qr_) v3_ = -1e30f; \
        } \
        float mx_ = fmaxf(fmaxf(v0_, v1_), fmaxf(v2_, v3_)); \
        mx_ = fmaxf(mx_, __shfl_xor(mx_, 1)); \
        mx_ = fmaxf(mx_, __shfl_xor(mx_, 2)); \
        mx_ = fmaxf(mx_, __shfl_xor(mx_, 4)); \
        mx_ = fmaxf(mx_, __shfl_xor(mx_, 8)); \
        float mnew_ = fmaxf(mrow[r], mx_); \
        float sc_ = __expf(mrow[r] - mnew_); \
        float p0_ = __expf(v0_ - mnew_), p1_ = __expf(v1_ - mnew_); \
        float p2_ = __expf(v2_ - mnew_), p3_ = __expf(v3_ - mnew_); \
        float rs_ = (p0_ + p1_) + (p2_ + p3_); \
        rs_ += __shfl_xor(rs_, 1); \
        rs_ += __shfl_xor(rs_, 2); \
        rs_ += __shfl_xor(rs_, 4); \
        rs_ += __shfl_xor(rs_, 8); \
        lrow[r] = lrow[r] * sc_ + rs_; \
        mrow[r] = mnew_; \
        o[0][r] *= sc_; o[1][r] *= sc_; o[2][r] *= sc_; o[3][r] *= sc_; \
        Plds[w][fg * 4 + r][     fr] = f2bf(p0_); \
        Plds[w][fg * 4 + r][16 + fr] = f2bf(p1_); \
        Plds[w][fg * 4 + r][32 + fr] = f2bf(p2_); \
        Plds[w][fg * 4 + r][48 + fr] = f2bf(p3_); \
    } \
    bf16x8 pf0_ = *(const bf16x8*)&Plds[w][fr][fg * 8]; \
    bf16x8 pf1_ = *(const bf16x8*)&Plds[w][fr][32 + fg * 8]; \
    _Pragma("unroll") \
    for (int j = 0; j < 4; ++j) { \
        o[j] = __builtin_amdgcn_mfma_f32_16x16x32_bf16(pf0_, vf_[j][0], o[j], 0, 0, 0); \
        o[j] = __builtin_amdgcn_mfma_f32_16x16x32_bf16(pf1_, vf_[j][1], o[j], 0, 0, 0); \
    } \
} while (0)

    if (t0 < t1) {
        bf16x8 kA[4][2], kB[4][2];
        int kt = t0;
        LDK(kA, t0);
        while (true) {
            LDK(kB, (kt + 1 < t1) ? kt + 1 : t1 - 1);
            PROCESS(kA, kt);
            ++kt; if (kt >= t1) break;
            LDK(kA, (kt + 1 < t1) ? kt + 1 : t1 - 1);
            PROCESS(kB, kt);
            ++kt; if (kt >= t1) break;
        }
    }
#undef LDK
#undef PROCESS

    u16* Op = s ? Op1 : Op0;
    float* mlp = mlbuf + (size_t)s * (NROWS * NHEADS * 2);
#pragma unroll
    for (int r = 0; r < 4; ++r) {
        int qrow = qbase + fg * 4 + r;
#pragma unroll
        for (int j = 0; j < 4; ++j)
            Op[(size_t)(bS + qrow) * 1024 + hd + j * 16 + fr] = f2bf(o[j][r]);
        if (fr == 0) {
            float* p = mlp + ((size_t)(bS + qrow) * NHEADS + h) * 2;
            p[0] = mrow[r];
            p[1] = lrow[r];
        }
    }
}

// ---------- combine the two split-K partials -> Mb ----------
__global__ void attn_combine(const u16* __restrict__ Op0, const u16* __restrict__ Op1,
                             const float* __restrict__ mlbuf, u16* __restrict__ Mb) {
    int i = blockIdx.x * blockDim.x + threadIdx.x;   // NROWS*1024/8 = 524288
    int row = i >> 7;
    int c   = (i & 127) * 8;
    int h   = c >> 6;
    const float* p0 = mlbuf + ((size_t)row * NHEADS + h) * 2;
    const float* p1 = p0 + (size_t)NROWS * NHEADS * 2;
    float m0 = p0[0], l0 = p0[1];
    float m1 = p1[0], l1 = p1[1];
    float m = fmaxf(m0, m1);
    float a0 = __expf(m0 - m), a1 = __expf(m1 - m);
    float linv = 1.0f / (l0 * a0 + l1 * a1);
    a0 *= linv; a1 *= linv;
    size_t base = (size_t)row * 1024 + c;
    uint4 u0 = *(const uint4*)(Op0 + base);
    uint4 u1 = *(const uint4*)(Op1 + base);
    const unsigned* w0 = (const unsigned*)&u0;
    const unsigned* w1 = (const unsigned*)&u1;
    unsigned ou[4];
#pragma unroll
    for (int k = 0; k < 4; ++k) {
        float x0 = bf2f((u16)(w0[k] & 0xffff)) * a0 + bf2f((u16)(w1[k] & 0xffff)) * a1;
        float x1 = bf2f((u16)(w0[k] >> 16)) * a0 + bf2f((u16)(w1[k] >> 16)) * a1;
        ou[k] = (unsigned)f2bf(x0) | ((unsigned)f2bf(x1) << 16);
    }
    *(uint4*)(Mb + base) = *(uint4*)ou;
}

extern "C" void kernel_launch(void* const* d_in, const int* in_sizes, int n_in,
                              void* d_out, int out_size, void* d_ws, size_t ws_size,
                              hipStream_t stream) {
    const float* x   = (const float*)d_in[0];
    const int*   pos = (const int*)d_in[1];
    const float* wq  = (const float*)d_in[2];
    const float* wk  = (const float*)d_in[3];
    const float* wv  = (const float*)d_in[4];
    const float* wo  = (const float*)d_in[5];
    float* out = (float*)d_out;

    char* ws = (char*)d_ws;
    u16* x2  = (u16*)(ws);                    // 16 MB split [4096][2048]; dead after QKV GEMMs
    u16* w2  = (u16*)(ws + (16ull << 20));    // 16 MB: wq2|wk2|wv2|wo2 split
    u16* wq2 = w2;
    u16* wk2 = w2 + 2048 * 1024;
    u16* wv2 = w2 + 2 * 2048 * 1024;
    u16* wo2 = w2 + 3 * 2048 * 1024;
    u16* Qp  = (u16*)(ws + (32ull << 20));    //  8 MB plain [4096][1024]
    u16* Kp  = (u16*)(ws + (40ull << 20));    //  8 MB plain
    u16* Vt  = (u16*)(ws + (48ull << 20));    //  8 MB plain transposed [1024][4096]
    u16* Mb  = (u16*)(ws + (56ull << 20));    //  8 MB plain [4096][1024]
    u16* Op0 = (u16*)(ws);                    //  8 MB partial O split 0 (reuses x2)
    u16* Op1 = (u16*)(ws + (8ull  << 20));    //  8 MB partial O split 1 (reuses x2)
    float* mlbuf = (float*)(ws + (64ull << 20));  // 1 MB [2][4096][16][2]

    // 1) convert inputs
    cvt_split<<<4096, 256, 0, stream>>>(x, x2, NROWS * 256);
    cvt_split4<<<4096, 256, 0, stream>>>(wq, wk, wv, wo, w2);

    // 2) QKV projections
    dim3 ggrid(NROWS / 128, D_MODEL / 128);
    gemm3<0><<<ggrid, 256, 0, stream>>>(x2, wq2, Qp, NROWS);
    gemm3<0><<<ggrid, 256, 0, stream>>>(x2, wk2, Kp, NROWS);
    gemm3<1><<<ggrid, 256, 0, stream>>>(x2, wv2, Vt, NROWS);

    // 3) RoPE in place
    rope_plain<<<16384, 256, 0, stream>>>(Qp, pos);

    // 4) causal flash attention, 2-way split-K + combine
    attn_v3<<<dim3(64, NHEADS, BATCH), 256, 0, stream>>>(Qp, Kp, Vt, Op0, Op1, mlbuf);
    attn_combine<<<2048, 256, 0, stream>>>(Op0, Op1, mlbuf, Mb);

    // 5) output projection
    gemm_out<<<ggrid, 256, 0, stream>>>(Mb, wo2, out);
}

// Round 6
// 316.060 us; speedup vs baseline: 1.6923x; 1.2175x over previous
//
#include <hip/hip_runtime.h>

#define D_MODEL 1024
#define SEQ     2048
#define BATCH   2
#define NHEADS  16
#define DK      64
#define NROWS   (BATCH*SEQ)   // 4096

typedef unsigned short u16;
typedef __bf16 bf16x8 __attribute__((ext_vector_type(8)));
typedef float  f32x4  __attribute__((ext_vector_type(4)));

__device__ __forceinline__ u16 f2bf(float f) {
    union { float f; unsigned u; } v; v.f = f;
    unsigned u = v.u;
    u += 0x7fffu + ((u >> 16) & 1);
    return (u16)(u >> 16);
}
__device__ __forceinline__ float bf2f(u16 h) {
    union { unsigned u; float f; } v; v.u = ((unsigned)h) << 16;
    return v.f;
}

__device__ __forceinline__ void gload_lds16(const u16* g, u16* l) {
    __builtin_amdgcn_global_load_lds(
        (const __attribute__((address_space(1))) void*)g,
        (__attribute__((address_space(3))) void*)l, 16, 0, 0);
}

// ---------- f32 [R][1024] -> bf16 split [R][2048] = [hi(1024) | lo(1024)] ----------
__global__ void cvt_split(const float* __restrict__ src, u16* __restrict__ dst, int total4) {
    int i = blockIdx.x * blockDim.x + threadIdx.x;
    if (i >= total4) return;
    int row = i >> 8;
    int c   = (i & 255) * 4;
    float4 v = *(const float4*)(src + (size_t)row * 1024 + c);
    u16 h0 = f2bf(v.x), h1 = f2bf(v.y), h2 = f2bf(v.z), h3 = f2bf(v.w);
    u16 l0 = f2bf(v.x - bf2f(h0)), l1 = f2bf(v.y - bf2f(h1));
    u16 l2 = f2bf(v.z - bf2f(h2)), l3 = f2bf(v.w - bf2f(h3));
    size_t b = (size_t)row * 2048;
    uint2 ph; ph.x = h0 | ((unsigned)h1 << 16); ph.y = h2 | ((unsigned)h3 << 16);
    uint2 pl; pl.x = l0 | ((unsigned)l1 << 16); pl.y = l2 | ((unsigned)l3 << 16);
    *(uint2*)&dst[b + c]        = ph;
    *(uint2*)&dst[b + 1024 + c] = pl;
}

__global__ void cvt_split4(const float* __restrict__ s0, const float* __restrict__ s1,
                           const float* __restrict__ s2, const float* __restrict__ s3,
                           u16* __restrict__ dst) {
    int i = blockIdx.x * blockDim.x + threadIdx.x;
    int wsel = i >> 18;
    int j = i & 262143;
    const float* src = wsel == 0 ? s0 : wsel == 1 ? s1 : wsel == 2 ? s2 : s3;
    int row = j >> 8;
    int c   = (j & 255) * 4;
    float4 v = *(const float4*)(src + (size_t)row * 1024 + c);
    u16 h0 = f2bf(v.x), h1 = f2bf(v.y), h2 = f2bf(v.z), h3 = f2bf(v.w);
    u16 l0 = f2bf(v.x - bf2f(h0)), l1 = f2bf(v.y - bf2f(h1));
    u16 l2 = f2bf(v.z - bf2f(h2)), l3 = f2bf(v.w - bf2f(h3));
    size_t b = (size_t)wsel * (2048 * 1024) + (size_t)row * 2048;
    uint2 ph; ph.x = h0 | ((unsigned)h1 << 16); ph.y = h2 | ((unsigned)h3 << 16);
    uint2 pl; pl.x = l0 | ((unsigned)l1 << 16); pl.y = l2 | ((unsigned)l3 << 16);
    *(uint2*)&dst[b + c]        = ph;
    *(uint2*)&dst[b + 1024 + c] = pl;
}

// ---------- split x split GEMM (3 MFMA), C plain bf16 ----------
template<int MODE>
__global__ __launch_bounds__(256) void gemm3(
    const u16* __restrict__ A2, const u16* __restrict__ B2, u16* __restrict__ Cout, int M)
{
    __shared__ __align__(16) u16 Ash[128 * 40];
    __shared__ __align__(16) u16 Asl[128 * 40];
    __shared__ __align__(16) u16 Bsh[128 * 40];
    __shared__ __align__(16) u16 Bsl[128 * 40];

    const int m0 = blockIdx.x * 128;
    const int n0 = blockIdx.y * 128;
    const int tid = threadIdx.x;
    const int lane = tid & 63;
    const int wid  = tid >> 6;
    const int wr = wid >> 1, wc = wid & 1;
    const int fr = lane & 15;
    const int fk = (lane >> 4) * 8;

    f32x4 acc[4][4];
#pragma unroll
    for (int i = 0; i < 4; ++i)
#pragma unroll
        for (int j = 0; j < 4; ++j) acc[i][j] = (f32x4){0.f, 0.f, 0.f, 0.f};

    for (int k0 = 0; k0 < 1024; k0 += 32) {
        __syncthreads();
#pragma unroll
        for (int s = 0; s < 2; ++s) {
            int c   = tid + s * 256;
            int row = c >> 2;
            int cb  = (c & 3) * 8;
            const u16* ap = A2 + (size_t)(m0 + row) * 2048 + k0 + cb;
            *(uint4*)&Ash[row * 40 + cb] = *(const uint4*)ap;
            *(uint4*)&Asl[row * 40 + cb] = *(const uint4*)(ap + 1024);
            const u16* bp = B2 + (size_t)(n0 + row) * 2048 + k0 + cb;
            *(uint4*)&Bsh[row * 40 + cb] = *(const uint4*)bp;
            *(uint4*)&Bsl[row * 40 + cb] = *(const uint4*)(bp + 1024);
        }
        __syncthreads();

        bf16x8 ah[4], al[4], bh[4], bl[4];
#pragma unroll
        for (int i = 0; i < 4; ++i) {
            ah[i] = *(const bf16x8*)&Ash[(wr * 64 + i * 16 + fr) * 40 + fk];
            al[i] = *(const bf16x8*)&Asl[(wr * 64 + i * 16 + fr) * 40 + fk];
        }
#pragma unroll
        for (int j = 0; j < 4; ++j) {
            bh[j] = *(const bf16x8*)&Bsh[(wc * 64 + j * 16 + fr) * 40 + fk];
            bl[j] = *(const bf16x8*)&Bsl[(wc * 64 + j * 16 + fr) * 40 + fk];
        }
#pragma unroll
        for (int i = 0; i < 4; ++i)
#pragma unroll
            for (int j = 0; j < 4; ++j) {
                acc[i][j] = __builtin_amdgcn_mfma_f32_16x16x32_bf16(ah[i], bh[j], acc[i][j], 0, 0, 0);
                acc[i][j] = __builtin_amdgcn_mfma_f32_16x16x32_bf16(al[i], bh[j], acc[i][j], 0, 0, 0);
                acc[i][j] = __builtin_amdgcn_mfma_f32_16x16x32_bf16(ah[i], bl[j], acc[i][j], 0, 0, 0);
            }
    }

    const int r0 = (lane >> 4) * 4;
#pragma unroll
    for (int i = 0; i < 4; ++i) {
        int row = m0 + wr * 64 + i * 16 + r0;
#pragma unroll
        for (int j = 0; j < 4; ++j) {
            int col = n0 + wc * 64 + j * 16 + fr;
#pragma unroll
            for (int r = 0; r < 4; ++r) {
                float v = acc[i][j][r];
                if (MODE == 0) Cout[(size_t)(row + r) * 1024 + col] = f2bf(v);
                else           Cout[(size_t)col * M + (row + r)]   = f2bf(v);
            }
        }
    }
}

// ---------- plain A x split B GEMM (2 MFMA), C f32 ----------
__global__ __launch_bounds__(256) void gemm_out(
    const u16* __restrict__ A, const u16* __restrict__ B2, float* __restrict__ Cout)
{
    __shared__ __align__(16) u16 Ash[128 * 40];
    __shared__ __align__(16) u16 Bsh[128 * 40];
    __shared__ __align__(16) u16 Bsl[128 * 40];

    const int m0 = blockIdx.x * 128;
    const int n0 = blockIdx.y * 128;
    const int tid = threadIdx.x;
    const int lane = tid & 63;
    const int wid  = tid >> 6;
    const int wr = wid >> 1, wc = wid & 1;
    const int fr = lane & 15;
    const int fk = (lane >> 4) * 8;

    f32x4 acc[4][4];
#pragma unroll
    for (int i = 0; i < 4; ++i)
#pragma unroll
        for (int j = 0; j < 4; ++j) acc[i][j] = (f32x4){0.f, 0.f, 0.f, 0.f};

    for (int k0 = 0; k0 < 1024; k0 += 32) {
        __syncthreads();
#pragma unroll
        for (int s = 0; s < 2; ++s) {
            int c   = tid + s * 256;
            int row = c >> 2;
            int cb  = (c & 3) * 8;
            *(uint4*)&Ash[row * 40 + cb] = *(const uint4*)(A + (size_t)(m0 + row) * 1024 + k0 + cb);
            const u16* bp = B2 + (size_t)(n0 + row) * 2048 + k0 + cb;
            *(uint4*)&Bsh[row * 40 + cb] = *(const uint4*)bp;
            *(uint4*)&Bsl[row * 40 + cb] = *(const uint4*)(bp + 1024);
        }
        __syncthreads();

        bf16x8 ah[4], bh[4], bl[4];
#pragma unroll
        for (int i = 0; i < 4; ++i)
            ah[i] = *(const bf16x8*)&Ash[(wr * 64 + i * 16 + fr) * 40 + fk];
#pragma unroll
        for (int j = 0; j < 4; ++j) {
            bh[j] = *(const bf16x8*)&Bsh[(wc * 64 + j * 16 + fr) * 40 + fk];
            bl[j] = *(const bf16x8*)&Bsl[(wc * 64 + j * 16 + fr) * 40 + fk];
        }
#pragma unroll
        for (int i = 0; i < 4; ++i)
#pragma unroll
            for (int j = 0; j < 4; ++j) {
                acc[i][j] = __builtin_amdgcn_mfma_f32_16x16x32_bf16(ah[i], bh[j], acc[i][j], 0, 0, 0);
                acc[i][j] = __builtin_amdgcn_mfma_f32_16x16x32_bf16(ah[i], bl[j], acc[i][j], 0, 0, 0);
            }
    }

    const int r0 = (lane >> 4) * 4;
#pragma unroll
    for (int i = 0; i < 4; ++i) {
        int row = m0 + wr * 64 + i * 16 + r0;
#pragma unroll
        for (int j = 0; j < 4; ++j) {
            int col = n0 + wc * 64 + j * 16 + fr;
#pragma unroll
            for (int r = 0; r < 4; ++r)
                Cout[(size_t)(row + r) * 1024 + col] = acc[i][j][r];
        }
    }
}

// ---------- RoPE in place on plain Q||K [8192][1024] ----------
__global__ void rope_plain(u16* __restrict__ qk, const int* __restrict__ pos) {
    int i = blockIdx.x * blockDim.x + threadIdx.x;
    int p = i & 511;
    int n = i >> 9;
    int s = n & 2047;
    int k = p & 31;
    int h = p >> 5;
    size_t base = (size_t)n * 1024 + h * DK + 2 * k;
    unsigned v = *(const unsigned*)&qk[base];
    float x0 = bf2f((u16)(v & 0xffff));
    float x1 = bf2f((u16)(v >> 16));
    float ang = (float)pos[s] * expf((float)k * -0.28782313662425575f);
    float c = cosf(ang), sn = sinf(ang);
    float y0 = x0 * c - x1 * sn;
    float y1 = x1 * c + x0 * sn;
    *(unsigned*)&qk[base] = (unsigned)f2bf(y0) | ((unsigned)f2bf(y1) << 16);
}

// ---------- causal flash attention v4 ----------
// 8 waves x 16 q-rows = 128 q-rows/block; swapped QK^T (lane-local softmax);
// K staged in LDS (global_load_lds, XOR-swizzled source); V direct from L2;
// 2-way balanced split-K; raw partials + ml like v3.
__global__ __launch_bounds__(512, 4) void attn_v4(
    const u16* __restrict__ Qp, const u16* __restrict__ Kp, const u16* __restrict__ Vt,
    u16* __restrict__ Op0, u16* __restrict__ Op1, float* __restrict__ mlbuf)
{
    const int qt2 = 15 - (int)(blockIdx.x >> 1);   // 128-row q tile, longest first
    const int s   = blockIdx.x & 1;
    const int h = blockIdx.y, b = blockIdx.z;
    const int tid  = threadIdx.x;
    const int lane = tid & 63;
    const int w    = tid >> 6;           // wave 0..7
    const int fr = lane & 15;
    const int fg = lane >> 4;
    const int bS = b * SEQ;
    const int hd = h * DK;
    const int qbase = qt2 * 128 + w * 16;

    const int half = qt2 + 1;            // tiles per split (balanced)
    const int t0 = s ? half : 0;
    const int t1 = s ? 2 * half : half;

    __shared__ __align__(16) u16 Kl[2][64 * 64];      // [buf][key][dk] linear, src-swizzled
    __shared__ __align__(16) u16 Plds[8][16][72];     // per-wave P transpose

    // Q fragments (B-operand: col=q=fr, k=fg*8+j)
    const u16* qrow = Qp + (size_t)(bS + qbase + fr) * 1024 + hd;
    bf16x8 qf0 = *(const bf16x8*)(qrow + fg * 8);
    bf16x8 qf1 = *(const bf16x8*)(qrow + 32 + fg * 8);

    f32x4 o[4];
#pragma unroll
    for (int j = 0; j < 4; ++j) o[j] = (f32x4){0.f, 0.f, 0.f, 0.f};
    float mrow = -1e30f, lrow = 0.f;     // stats for query qbase+fr (fr-space)

    // staging geometry: wave w stages rows [8w, 8w+8) of the tile, 1 KB per call.
    // LDS dest linear; global source column pre-swizzled: chunk (l&7) ^ (l>>3).
    const int srow = 8 * w + (lane >> 3);
    const int scol = (((lane & 7) ^ (lane >> 3)) * 8);
    const int swz  = (fr & 7) * 8;       // read-side XOR (u16 units)

#define STAGE(BUF, KT) do { \
    const u16* gs_ = Kp + (size_t)(bS + (KT) * 64 + srow) * 1024 + hd + scol; \
    gload_lds16(gs_, &Kl[BUF][8 * w * 64]); \
} while (0)

    STAGE(0, t0);
    __syncthreads();

    int cur = 0;
    for (int kt = t0; kt < t1; ++kt) {
        if (kt + 1 < t1) STAGE(cur ^ 1, kt + 1);
        const int k0 = kt * 64;
        if (k0 <= qbase + 15) {                      // wave-uniform participation
            const u16* Kb = Kl[cur];
            // K A-frags from LDS (row=16t+fr, dk chunk fg / 4+fg, XOR-swizzled)
            bf16x8 kf[4][2];
#pragma unroll
            for (int t = 0; t < 4; ++t) {
                const u16* kr = Kb + (16 * t + fr) * 64;
                kf[t][0] = *(const bf16x8*)(kr + ((fg * 8) ^ swz));
                kf[t][1] = *(const bf16x8*)(kr + (((4 + fg) * 8) ^ swz));
            }
            // QK^T swapped: C[key=4fg+r][q=fr]
            f32x4 sc4[4];
#pragma unroll
            for (int t = 0; t < 4; ++t) {
                f32x4 a = (f32x4){0.f, 0.f, 0.f, 0.f};
                a = __builtin_amdgcn_mfma_f32_16x16x32_bf16(kf[t][0], qf0, a, 0, 0, 0);
                a = __builtin_amdgcn_mfma_f32_16x16x32_bf16(kf[t][1], qf1, a, 0, 0, 0);
                sc4[t] = a;
            }
            // V B-frags direct from global (L2-resident), issued early
            bf16x8 vf[4][2];
#pragma unroll
            for (int j = 0; j < 4; ++j) {
                const u16* vp = Vt + (size_t)(hd + 16 * j + fr) * NROWS + bS + k0;
                vf[j][0] = *(const bf16x8*)(vp + fg * 8);
                vf[j][1] = *(const bf16x8*)(vp + 32 + fg * 8);
            }
            // mask + scale (16 scores, all for query qbase+fr)
            float p[4][4];
            const bool dg = (k0 + 63 > qbase);
#pragma unroll
            for (int t = 0; t < 4; ++t)
#pragma unroll
                for (int r = 0; r < 4; ++r) {
                    float v = sc4[t][r] * 0.125f;
                    if (dg && (k0 + 16 * t + 4 * fg + r > qbase + fr)) v = -1e30f;
                    p[t][r] = v;
                }
            // in-lane max tree + 2 shfls
            float mx = p[0][0];
#pragma unroll
            for (int t = 0; t < 4; ++t)
#pragma unroll
                for (int r = 0; r < 4; ++r) mx = fmaxf(mx, p[t][r]);
            mx = fmaxf(mx, __shfl_xor(mx, 16));
            mx = fmaxf(mx, __shfl_xor(mx, 32));
            float mnew = fmaxf(mrow, mx);
            float scf = __expf(mrow - mnew);
            mrow = mnew;
            float rs = 0.f;
#pragma unroll
            for (int t = 0; t < 4; ++t)
#pragma unroll
                for (int r = 0; r < 4; ++r) {
                    p[t][r] = __expf(p[t][r] - mnew);
                    rs += p[t][r];
                }
            rs += __shfl_xor(rs, 16);
            rs += __shfl_xor(rs, 32);
            lrow = lrow * scf + rs;
            // redistribute rescale factor from fr-space to o-space (q = 4fg+r)
            float scr[4];
#pragma unroll
            for (int r = 0; r < 4; ++r) scr[r] = __shfl(scf, 4 * fg + r);
#pragma unroll
            for (int j = 0; j < 4; ++j)
#pragma unroll
                for (int r = 0; r < 4; ++r) o[j][r] *= scr[r];
            // P transpose through per-wave LDS: write [q=fr][key], read A-frags
#pragma unroll
            for (int t = 0; t < 4; ++t)
#pragma unroll
                for (int r = 0; r < 4; ++r)
                    Plds[w][fr][16 * t + 4 * fg + r] = f2bf(p[t][r]);
            bf16x8 pf0 = *(const bf16x8*)&Plds[w][fr][fg * 8];
            bf16x8 pf1 = *(const bf16x8*)&Plds[w][fr][32 + fg * 8];
            // PV: O[q=4fg+r][d=16j+fr]
#pragma unroll
            for (int j = 0; j < 4; ++j) {
                o[j] = __builtin_amdgcn_mfma_f32_16x16x32_bf16(pf0, vf[j][0], o[j], 0, 0, 0);
                o[j] = __builtin_amdgcn_mfma_f32_16x16x32_bf16(pf1, vf[j][1], o[j], 0, 0, 0);
            }
        }
        __syncthreads();
        cur ^= 1;
    }
#undef STAGE

    u16* Op = s ? Op1 : Op0;
    float* mlp = mlbuf + (size_t)s * (NROWS * NHEADS * 2);
#pragma unroll
    for (int r = 0; r < 4; ++r) {
        int qrow = qbase + 4 * fg + r;
#pragma unroll
        for (int j = 0; j < 4; ++j)
            Op[(size_t)(bS + qrow) * 1024 + hd + 16 * j + fr] = f2bf(o[j][r]);
    }
    if (fg == 0) {
        float* pp = mlp + ((size_t)(bS + qbase + fr) * NHEADS + h) * 2;
        pp[0] = mrow;
        pp[1] = lrow;
    }
}

// ---------- combine the two split-K partials -> Mb ----------
__global__ void attn_combine(const u16* __restrict__ Op0, const u16* __restrict__ Op1,
                             const float* __restrict__ mlbuf, u16* __restrict__ Mb) {
    int i = blockIdx.x * blockDim.x + threadIdx.x;   // NROWS*1024/8 = 524288
    int row = i >> 7;
    int c   = (i & 127) * 8;
    int h   = c >> 6;
    const float* p0 = mlbuf + ((size_t)row * NHEADS + h) * 2;
    const float* p1 = p0 + (size_t)NROWS * NHEADS * 2;
    float m0 = p0[0], l0 = p0[1];
    float m1 = p1[0], l1 = p1[1];
    float m = fmaxf(m0, m1);
    float a0 = __expf(m0 - m), a1 = __expf(m1 - m);
    float linv = 1.0f / (l0 * a0 + l1 * a1);
    a0 *= linv; a1 *= linv;
    size_t base = (size_t)row * 1024 + c;
    uint4 u0 = *(const uint4*)(Op0 + base);
    uint4 u1 = *(const uint4*)(Op1 + base);
    const unsigned* w0 = (const unsigned*)&u0;
    const unsigned* w1 = (const unsigned*)&u1;
    unsigned ou[4];
#pragma unroll
    for (int k = 0; k < 4; ++k) {
        float x0 = bf2f((u16)(w0[k] & 0xffff)) * a0 + bf2f((u16)(w1[k] & 0xffff)) * a1;
        float x1 = bf2f((u16)(w0[k] >> 16)) * a0 + bf2f((u16)(w1[k] >> 16)) * a1;
        ou[k] = (unsigned)f2bf(x0) | ((unsigned)f2bf(x1) << 16);
    }
    *(uint4*)(Mb + base) = *(uint4*)ou;
}

extern "C" void kernel_launch(void* const* d_in, const int* in_sizes, int n_in,
                              void* d_out, int out_size, void* d_ws, size_t ws_size,
                              hipStream_t stream) {
    const float* x   = (const float*)d_in[0];
    const int*   pos = (const int*)d_in[1];
    const float* wq  = (const float*)d_in[2];
    const float* wk  = (const float*)d_in[3];
    const float* wv  = (const float*)d_in[4];
    const float* wo  = (const float*)d_in[5];
    float* out = (float*)d_out;

    char* ws = (char*)d_ws;
    u16* x2  = (u16*)(ws);                    // 16 MB split [4096][2048]; dead after QKV GEMMs
    u16* w2  = (u16*)(ws + (16ull << 20));    // 16 MB: wq2|wk2|wv2|wo2 split
    u16* wq2 = w2;
    u16* wk2 = w2 + 2048 * 1024;
    u16* wv2 = w2 + 2 * 2048 * 1024;
    u16* wo2 = w2 + 3 * 2048 * 1024;
    u16* Qp  = (u16*)(ws + (32ull << 20));    //  8 MB plain [4096][1024]
    u16* Kp  = (u16*)(ws + (40ull << 20));    //  8 MB plain
    u16* Vt  = (u16*)(ws + (48ull << 20));    //  8 MB plain transposed [1024][4096]
    u16* Mb  = (u16*)(ws + (56ull << 20));    //  8 MB plain [4096][1024]
    u16* Op0 = (u16*)(ws);                    //  8 MB partial O split 0 (reuses x2)
    u16* Op1 = (u16*)(ws + (8ull  << 20));    //  8 MB partial O split 1 (reuses x2)
    float* mlbuf = (float*)(ws + (64ull << 20));  // 1 MB [2][4096][16][2]

    // 1) convert inputs
    cvt_split<<<4096, 256, 0, stream>>>(x, x2, NROWS * 256);
    cvt_split4<<<4096, 256, 0, stream>>>(wq, wk, wv, wo, w2);

    // 2) QKV projections
    dim3 ggrid(NROWS / 128, D_MODEL / 128);
    gemm3<0><<<ggrid, 256, 0, stream>>>(x2, wq2, Qp, NROWS);
    gemm3<0><<<ggrid, 256, 0, stream>>>(x2, wk2, Kp, NROWS);
    gemm3<1><<<ggrid, 256, 0, stream>>>(x2, wv2, Vt, NROWS);

    // 3) RoPE in place
    rope_plain<<<16384, 256, 0, stream>>>(Qp, pos);

    // 4) causal flash attention v4 (8-wave, LDS-K, swapped-QK) + combine
    attn_v4<<<dim3(32, NHEADS, BATCH), 512, 0, stream>>>(Qp, Kp, Vt, Op0, Op1, mlbuf);
    attn_combine<<<2048, 256, 0, stream>>>(Op0, Op1, mlbuf, Mb);

    // 5) output projection
    gemm_out<<<ggrid, 256, 0, stream>>>(Mb, wo2, out);
}

// Round 7
// 307.403 us; speedup vs baseline: 1.7400x; 1.0282x over previous
//
#include <hip/hip_runtime.h>

#define D_MODEL 1024
#define SEQ     2048
#define BATCH   2
#define NHEADS  16
#define DK      64
#define NROWS   (BATCH*SEQ)   // 4096

typedef unsigned short u16;
typedef __bf16 bf16x8 __attribute__((ext_vector_type(8)));
typedef float  f32x4  __attribute__((ext_vector_type(4)));

__device__ __forceinline__ u16 f2bf(float f) {
    union { float f; unsigned u; } v; v.f = f;
    unsigned u = v.u;
    u += 0x7fffu + ((u >> 16) & 1);
    return (u16)(u >> 16);
}
__device__ __forceinline__ float bf2f(u16 h) {
    union { unsigned u; float f; } v; v.u = ((unsigned)h) << 16;
    return v.f;
}

__device__ __forceinline__ void gload_lds16(const u16* g, u16* l) {
    __builtin_amdgcn_global_load_lds(
        (const __attribute__((address_space(1))) void*)g,
        (__attribute__((address_space(3))) void*)l, 16, 0, 0);
}

// ---------- f32 [R][1024] -> bf16 split [R][2048] = [hi(1024) | lo(1024)] ----------
__global__ void cvt_split(const float* __restrict__ src, u16* __restrict__ dst, int total4) {
    int i = blockIdx.x * blockDim.x + threadIdx.x;
    if (i >= total4) return;
    int row = i >> 8;
    int c   = (i & 255) * 4;
    float4 v = *(const float4*)(src + (size_t)row * 1024 + c);
    u16 h0 = f2bf(v.x), h1 = f2bf(v.y), h2 = f2bf(v.z), h3 = f2bf(v.w);
    u16 l0 = f2bf(v.x - bf2f(h0)), l1 = f2bf(v.y - bf2f(h1));
    u16 l2 = f2bf(v.z - bf2f(h2)), l3 = f2bf(v.w - bf2f(h3));
    size_t b = (size_t)row * 2048;
    uint2 ph; ph.x = h0 | ((unsigned)h1 << 16); ph.y = h2 | ((unsigned)h3 << 16);
    uint2 pl; pl.x = l0 | ((unsigned)l1 << 16); pl.y = l2 | ((unsigned)l3 << 16);
    *(uint2*)&dst[b + c]        = ph;
    *(uint2*)&dst[b + 1024 + c] = pl;
}

__global__ void cvt_split4(const float* __restrict__ s0, const float* __restrict__ s1,
                           const float* __restrict__ s2, const float* __restrict__ s3,
                           u16* __restrict__ dst) {
    int i = blockIdx.x * blockDim.x + threadIdx.x;
    int wsel = i >> 18;
    int j = i & 262143;
    const float* src = wsel == 0 ? s0 : wsel == 1 ? s1 : wsel == 2 ? s2 : s3;
    int row = j >> 8;
    int c   = (j & 255) * 4;
    float4 v = *(const float4*)(src + (size_t)row * 1024 + c);
    u16 h0 = f2bf(v.x), h1 = f2bf(v.y), h2 = f2bf(v.z), h3 = f2bf(v.w);
    u16 l0 = f2bf(v.x - bf2f(h0)), l1 = f2bf(v.y - bf2f(h1));
    u16 l2 = f2bf(v.z - bf2f(h2)), l3 = f2bf(v.w - bf2f(h3));
    size_t b = (size_t)wsel * (2048 * 1024) + (size_t)row * 2048;
    uint2 ph; ph.x = h0 | ((unsigned)h1 << 16); ph.y = h2 | ((unsigned)h3 << 16);
    uint2 pl; pl.x = l0 | ((unsigned)l1 << 16); pl.y = l2 | ((unsigned)l3 << 16);
    *(uint2*)&dst[b + c]        = ph;
    *(uint2*)&dst[b + 1024 + c] = pl;
}

// ---------- merged QKV GEMM: split x split (3 MFMA), global_load_lds staging ----------
// blockIdx.y: [0,8)=Q, [8,16)=K, [16,24)=V(transposed out)
__global__ __launch_bounds__(256) void gemm_qkv(
    const u16* __restrict__ A2, const u16* __restrict__ W2,
    u16* __restrict__ Qp, u16* __restrict__ Kp, u16* __restrict__ Vt)
{
    __shared__ __align__(16) u16 Ash[128 * 32];
    __shared__ __align__(16) u16 Asl[128 * 32];
    __shared__ __align__(16) u16 Bsh[128 * 32];
    __shared__ __align__(16) u16 Bsl[128 * 32];

    const int m0  = blockIdx.x * 128;
    const int sel = blockIdx.y >> 3;
    const int n0  = (blockIdx.y & 7) * 128;
    const u16* B2 = W2 + (size_t)sel * (2048 * 1024);
    const int tid = threadIdx.x;
    const int lane = tid & 63;
    const int w    = tid >> 6;
    const int wr = w >> 1, wc = w & 1;
    const int fr = lane & 15;
    const int fk = (lane >> 4) * 8;
    const int rsub = lane >> 2;        // staging row within 16-row group
    const int csub = (lane & 3) * 8;   // staging col chunk (u16)

    f32x4 acc[4][4];
#pragma unroll
    for (int i = 0; i < 4; ++i)
#pragma unroll
        for (int j = 0; j < 4; ++j) acc[i][j] = (f32x4){0.f, 0.f, 0.f, 0.f};

    for (int k0 = 0; k0 < 1024; k0 += 32) {
        __syncthreads();
        const u16* Ab = A2 + (size_t)(m0 + 16 * w + rsub) * 2048 + k0 + csub;
        const u16* Bb = B2 + (size_t)(n0 + 16 * w + rsub) * 2048 + k0 + csub;
#pragma unroll
        for (int half = 0; half < 2; ++half) {
            size_t ro = (size_t)(half * 64) * 2048;
            int lo = (half * 64 + 16 * w) * 32;
            gload_lds16(Ab + ro,        &Ash[lo]);
            gload_lds16(Ab + ro + 1024, &Asl[lo]);
            gload_lds16(Bb + ro,        &Bsh[lo]);
            gload_lds16(Bb + ro + 1024, &Bsl[lo]);
        }
        __syncthreads();

        bf16x8 ah[4], al[4], bh[4], bl[4];
#pragma unroll
        for (int i = 0; i < 4; ++i) {
            ah[i] = *(const bf16x8*)&Ash[(wr * 64 + i * 16 + fr) * 32 + fk];
            al[i] = *(const bf16x8*)&Asl[(wr * 64 + i * 16 + fr) * 32 + fk];
        }
#pragma unroll
        for (int j = 0; j < 4; ++j) {
            bh[j] = *(const bf16x8*)&Bsh[(wc * 64 + j * 16 + fr) * 32 + fk];
            bl[j] = *(const bf16x8*)&Bsl[(wc * 64 + j * 16 + fr) * 32 + fk];
        }
#pragma unroll
        for (int i = 0; i < 4; ++i)
#pragma unroll
            for (int j = 0; j < 4; ++j) {
                acc[i][j] = __builtin_amdgcn_mfma_f32_16x16x32_bf16(ah[i], bh[j], acc[i][j], 0, 0, 0);
                acc[i][j] = __builtin_amdgcn_mfma_f32_16x16x32_bf16(al[i], bh[j], acc[i][j], 0, 0, 0);
                acc[i][j] = __builtin_amdgcn_mfma_f32_16x16x32_bf16(ah[i], bl[j], acc[i][j], 0, 0, 0);
            }
    }

    const int r0 = (lane >> 4) * 4;
#pragma unroll
    for (int i = 0; i < 4; ++i) {
#pragma unroll
        for (int j = 0; j < 4; ++j) {
            int col = n0 + wc * 64 + j * 16 + fr;
#pragma unroll
            for (int r = 0; r < 4; ++r) {
                int row = m0 + wr * 64 + i * 16 + r0 + r;
                u16 v = f2bf(acc[i][j][r]);
                if (sel == 0)      Qp[(size_t)row * 1024 + col] = v;
                else if (sel == 1) Kp[(size_t)row * 1024 + col] = v;
                else               Vt[(size_t)col * NROWS + row] = v;
            }
        }
    }
}

// ---------- output GEMM: plain A x split B (2 MFMA), gload_lds staging, f32 out ----------
__global__ __launch_bounds__(256) void gemm_out(
    const u16* __restrict__ A, const u16* __restrict__ B2, float* __restrict__ Cout)
{
    __shared__ __align__(16) u16 Ash[128 * 32];
    __shared__ __align__(16) u16 Bsh[128 * 32];
    __shared__ __align__(16) u16 Bsl[128 * 32];

    const int m0 = blockIdx.x * 128;
    const int n0 = blockIdx.y * 128;
    const int tid = threadIdx.x;
    const int lane = tid & 63;
    const int w    = tid >> 6;
    const int wr = w >> 1, wc = w & 1;
    const int fr = lane & 15;
    const int fk = (lane >> 4) * 8;
    const int rsub = lane >> 2;
    const int csub = (lane & 3) * 8;

    f32x4 acc[4][4];
#pragma unroll
    for (int i = 0; i < 4; ++i)
#pragma unroll
        for (int j = 0; j < 4; ++j) acc[i][j] = (f32x4){0.f, 0.f, 0.f, 0.f};

    for (int k0 = 0; k0 < 1024; k0 += 32) {
        __syncthreads();
        const u16* Ab = A  + (size_t)(m0 + 16 * w + rsub) * 1024 + k0 + csub;
        const u16* Bb = B2 + (size_t)(n0 + 16 * w + rsub) * 2048 + k0 + csub;
#pragma unroll
        for (int half = 0; half < 2; ++half) {
            int lo = (half * 64 + 16 * w) * 32;
            gload_lds16(Ab + (size_t)(half * 64) * 1024,        &Ash[lo]);
            gload_lds16(Bb + (size_t)(half * 64) * 2048,        &Bsh[lo]);
            gload_lds16(Bb + (size_t)(half * 64) * 2048 + 1024, &Bsl[lo]);
        }
        __syncthreads();

        bf16x8 ah[4], bh[4], bl[4];
#pragma unroll
        for (int i = 0; i < 4; ++i)
            ah[i] = *(const bf16x8*)&Ash[(wr * 64 + i * 16 + fr) * 32 + fk];
#pragma unroll
        for (int j = 0; j < 4; ++j) {
            bh[j] = *(const bf16x8*)&Bsh[(wc * 64 + j * 16 + fr) * 32 + fk];
            bl[j] = *(const bf16x8*)&Bsl[(wc * 64 + j * 16 + fr) * 32 + fk];
        }
#pragma unroll
        for (int i = 0; i < 4; ++i)
#pragma unroll
            for (int j = 0; j < 4; ++j) {
                acc[i][j] = __builtin_amdgcn_mfma_f32_16x16x32_bf16(ah[i], bh[j], acc[i][j], 0, 0, 0);
                acc[i][j] = __builtin_amdgcn_mfma_f32_16x16x32_bf16(ah[i], bl[j], acc[i][j], 0, 0, 0);
            }
    }

    const int r0 = (lane >> 4) * 4;
#pragma unroll
    for (int i = 0; i < 4; ++i) {
#pragma unroll
        for (int j = 0; j < 4; ++j) {
            int col = n0 + wc * 64 + j * 16 + fr;
#pragma unroll
            for (int r = 0; r < 4; ++r)
                Cout[(size_t)(m0 + wr * 64 + i * 16 + r0 + r) * 1024 + col] = acc[i][j][r];
        }
    }
}

// ---------- RoPE in place on plain Q||K [8192][1024] ----------
__global__ void rope_plain(u16* __restrict__ qk, const int* __restrict__ pos) {
    int i = blockIdx.x * blockDim.x + threadIdx.x;
    int p = i & 511;
    int n = i >> 9;
    int s = n & 2047;
    int k = p & 31;
    int h = p >> 5;
    size_t base = (size_t)n * 1024 + h * DK + 2 * k;
    unsigned v = *(const unsigned*)&qk[base];
    float x0 = bf2f((u16)(v & 0xffff));
    float x1 = bf2f((u16)(v >> 16));
    float ang = (float)pos[s] * expf((float)k * -0.28782313662425575f);
    float c = cosf(ang), sn = sinf(ang);
    float y0 = x0 * c - x1 * sn;
    float y1 = x1 * c + x0 * sn;
    *(unsigned*)&qk[base] = (unsigned)f2bf(y0) | ((unsigned)f2bf(y1) << 16);
}

// ---------- causal flash attention v5 ----------
// Barrier-free: K and V frags direct from global (L2-resident); 4 waves x 16 q-rows;
// fixed 8-tile (512-key) chunks for balance; per-chunk raw partials + ml.
// slot table per (h,b): qt has ceil((qt+1)/8) chunks; S8(qt)=4g(g+1)+(qt&7)(g+1), g=qt>>3.
__global__ __launch_bounds__(256, 4) void attn_v5(
    const u16* __restrict__ Qp, const u16* __restrict__ Kp, const u16* __restrict__ Vt,
    u16* __restrict__ Op, float* __restrict__ mlbuf)
{
    const int slot = 79 - (int)blockIdx.x;      // longest chunks dispatch first
    const int h = blockIdx.y, b = blockIdx.z;
    int qt, c;
    if (slot < 8)       { qt = slot;                               c = 0; }
    else if (slot < 24) { int r = slot - 8;  qt = 8  + (r >> 1);   c = r & 1; }
    else if (slot < 48) { int r = slot - 24; int q3 = r / 3; qt = 16 + q3; c = r - 3 * q3; }
    else                { int r = slot - 48; qt = 24 + (r >> 2);   c = r & 3; }

    const int lane = threadIdx.x & 63;
    const int w    = threadIdx.x >> 6;
    const int fr = lane & 15;
    const int fg = lane >> 4;
    const int bS = b * SEQ;
    const int hd = h * DK;
    const int qbase = qt * 64 + 16 * w;
    const int kt0 = 8 * c;
    const int kt1 = min(8 * c + 8, qt + 1);

    __shared__ __align__(16) u16 Plds[4][16][72];

    const u16* qrow = Qp + (size_t)(bS + qbase + fr) * 1024 + hd;
    bf16x8 qf0 = *(const bf16x8*)(qrow + fg * 8);
    bf16x8 qf1 = *(const bf16x8*)(qrow + 32 + fg * 8);

    f32x4 o[4];
#pragma unroll
    for (int j = 0; j < 4; ++j) o[j] = (f32x4){0.f, 0.f, 0.f, 0.f};
    float mrow = -1e30f, lrow = 0.f;

    for (int kt = kt0; kt < kt1; ++kt) {
        const int k0 = kt * 64;
        // K frags direct from global (A-operand: row=key)
        bf16x8 kf[4][2];
#pragma unroll
        for (int t = 0; t < 4; ++t) {
            const u16* kp = Kp + (size_t)(bS + k0 + 16 * t + fr) * 1024 + hd;
            kf[t][0] = *(const bf16x8*)(kp + fg * 8);
            kf[t][1] = *(const bf16x8*)(kp + 32 + fg * 8);
        }
        f32x4 sc4[4];
#pragma unroll
        for (int t = 0; t < 4; ++t) {
            f32x4 a = (f32x4){0.f, 0.f, 0.f, 0.f};
            a = __builtin_amdgcn_mfma_f32_16x16x32_bf16(kf[t][0], qf0, a, 0, 0, 0);
            a = __builtin_amdgcn_mfma_f32_16x16x32_bf16(kf[t][1], qf1, a, 0, 0, 0);
            sc4[t] = a;
        }
        // mask + scale (lane holds 16 scores for query qbase+fr)
        float p[4][4];
        const bool dg = (kt == qt);
#pragma unroll
        for (int t = 0; t < 4; ++t)
#pragma unroll
            for (int r = 0; r < 4; ++r) {
                float v = sc4[t][r] * 0.125f;
                if (dg && (k0 + 16 * t + 4 * fg + r > qbase + fr)) v = -1e30f;
                p[t][r] = v;
            }
        float mx = p[0][0];
#pragma unroll
        for (int t = 0; t < 4; ++t)
#pragma unroll
            for (int r = 0; r < 4; ++r) mx = fmaxf(mx, p[t][r]);
        mx = fmaxf(mx, __shfl_xor(mx, 16));
        mx = fmaxf(mx, __shfl_xor(mx, 32));
        float mnew = fmaxf(mrow, mx);
        float scf = __expf(mrow - mnew);
        mrow = mnew;
        float rs = 0.f;
#pragma unroll
        for (int t = 0; t < 4; ++t)
#pragma unroll
            for (int r = 0; r < 4; ++r) {
                p[t][r] = __expf(p[t][r] - mnew);
                rs += p[t][r];
            }
        rs += __shfl_xor(rs, 16);
        rs += __shfl_xor(rs, 32);
        lrow = lrow * scf + rs;
        // redistribute rescale factor: o-space query = 4*fg+r lives in lane (4*fg+r)
        float scr[4];
#pragma unroll
        for (int r = 0; r < 4; ++r) scr[r] = __shfl(scf, 4 * fg + r);
#pragma unroll
        for (int j = 0; j < 4; ++j)
#pragma unroll
            for (int r = 0; r < 4; ++r) o[j][r] *= scr[r];
        // P transpose through per-wave LDS (wave-private, no barrier)
#pragma unroll
        for (int t = 0; t < 4; ++t)
#pragma unroll
            for (int r = 0; r < 4; ++r)
                Plds[w][fr][16 * t + 4 * fg + r] = f2bf(p[t][r]);
        bf16x8 pf0 = *(const bf16x8*)&Plds[w][fr][fg * 8];
        bf16x8 pf1 = *(const bf16x8*)&Plds[w][fr][32 + fg * 8];
        // V frags (B-operand: col=output dim), loaded post-softmax to bound VGPR
#pragma unroll
        for (int j = 0; j < 4; ++j) {
            const u16* vp = Vt + (size_t)(hd + 16 * j + fr) * NROWS + bS + k0;
            bf16x8 v0 = *(const bf16x8*)(vp + fg * 8);
            bf16x8 v1 = *(const bf16x8*)(vp + 32 + fg * 8);
            o[j] = __builtin_amdgcn_mfma_f32_16x16x32_bf16(pf0, v0, o[j], 0, 0, 0);
            o[j] = __builtin_amdgcn_mfma_f32_16x16x32_bf16(pf1, v1, o[j], 0, 0, 0);
        }
    }

    const int slotg = (b * NHEADS + h) * 80 + slot;
#pragma unroll
    for (int r = 0; r < 4; ++r) {
        int rrel = 16 * w + 4 * fg + r;
#pragma unroll
        for (int j = 0; j < 4; ++j)
            Op[((size_t)slotg * 64 + rrel) * 64 + 16 * j + fr] = f2bf(o[j][r]);
    }
    if (fg == 0) {
        float* pp = mlbuf + ((size_t)slotg * 64 + 16 * w + fr) * 2;
        pp[0] = mrow;
        pp[1] = lrow;
    }
}

// ---------- combine up-to-4 split-K partials -> Mb ----------
__global__ void attn_combine2(const u16* __restrict__ Op, const float* __restrict__ mlbuf,
                              u16* __restrict__ Mb) {
    int i = blockIdx.x * blockDim.x + threadIdx.x;   // 4096*128 = 524288
    int row = i >> 7;            // 0..4095
    int c8  = (i & 127) * 8;     // col 0..1016
    int h   = c8 >> 6;
    int s   = row & 2047;
    int b   = row >> 11;
    int qt  = s >> 6;
    int g   = qt >> 3;
    int nch = g + 1;
    int slot0 = (b * NHEADS + h) * 80 + 4 * g * (g + 1) + (qt & 7) * (g + 1);
    int rrel = s & 63, crel = c8 & 63;

    float mv[4], lv[4];
    float m = -1e30f;
    for (int k = 0; k < nch; ++k) {
        const float* pp = mlbuf + ((size_t)(slot0 + k) * 64 + rrel) * 2;
        mv[k] = pp[0]; lv[k] = pp[1];
        m = fmaxf(m, mv[k]);
    }
    float L = 0.f;
    for (int k = 0; k < nch; ++k) {
        mv[k] = __expf(mv[k] - m);     // reuse as weight
        L += lv[k] * mv[k];
    }
    float acc[8];
#pragma unroll
    for (int jj = 0; jj < 8; ++jj) acc[jj] = 0.f;
    for (int k = 0; k < nch; ++k) {
        float wgt = mv[k];
        uint4 u = *(const uint4*)(Op + ((size_t)(slot0 + k) * 64 + rrel) * 64 + crel);
        const unsigned* wrd = (const unsigned*)&u;
#pragma unroll
        for (int kk = 0; kk < 4; ++kk) {
            acc[2 * kk]     += wgt * bf2f((u16)(wrd[kk] & 0xffff));
            acc[2 * kk + 1] += wgt * bf2f((u16)(wrd[kk] >> 16));
        }
    }
    float inv = 1.0f / L;
    unsigned ou[4];
#pragma unroll
    for (int kk = 0; kk < 4; ++kk)
        ou[kk] = (unsigned)f2bf(acc[2 * kk] * inv) | ((unsigned)f2bf(acc[2 * kk + 1] * inv) << 16);
    *(uint4*)(Mb + (size_t)row * 1024 + c8) = *(uint4*)ou;
}

extern "C" void kernel_launch(void* const* d_in, const int* in_sizes, int n_in,
                              void* d_out, int out_size, void* d_ws, size_t ws_size,
                              hipStream_t stream) {
    const float* x   = (const float*)d_in[0];
    const int*   pos = (const int*)d_in[1];
    const float* wq  = (const float*)d_in[2];
    const float* wk  = (const float*)d_in[3];
    const float* wv  = (const float*)d_in[4];
    const float* wo  = (const float*)d_in[5];
    float* out = (float*)d_out;

    char* ws = (char*)d_ws;
    u16* x2  = (u16*)(ws);                    // 16 MB split [4096][2048]; dead after QKV
    u16* w2  = (u16*)(ws + (16ull << 20));    // 16 MB: wq2|wk2|wv2|wo2 split
    u16* wo2 = w2 + 3 * 2048 * 1024;          // [28,32) — must survive to the end
    u16* Qp  = (u16*)(ws + (32ull << 20));    //  8 MB plain [4096][1024]
    u16* Kp  = (u16*)(ws + (40ull << 20));    //  8 MB plain
    u16* Vt  = (u16*)(ws + (48ull << 20));    //  8 MB plain transposed [1024][4096]
    u16* Mb  = (u16*)(ws + (56ull << 20));    //  8 MB plain [4096][1024]
    u16* Op  = (u16*)(ws);                    // 21 MB partials (reuses x2/wq2; dead inputs)
    float* mlbuf = (float*)(ws + (21ull << 20)); // 1.3 MB (within dead wk2 region)

    // 1) convert inputs
    cvt_split<<<4096, 256, 0, stream>>>(x, x2, NROWS * 256);
    cvt_split4<<<4096, 256, 0, stream>>>(wq, wk, wv, wo, w2);

    // 2) merged QKV projection (split x split, 3-MFMA, gload_lds staging)
    gemm_qkv<<<dim3(NROWS / 128, 24), 256, 0, stream>>>(x2, w2, Qp, Kp, Vt);

    // 3) RoPE in place
    rope_plain<<<16384, 256, 0, stream>>>(Qp, pos);

    // 4) causal flash attention v5 (barrier-free, balanced chunks) + combine
    attn_v5<<<dim3(80, NHEADS, BATCH), 256, 0, stream>>>(Qp, Kp, Vt, Op, mlbuf);
    attn_combine2<<<2048, 256, 0, stream>>>(Op, mlbuf, Mb);

    // 5) output projection
    gemm_out<<<dim3(NROWS / 128, 8), 256, 0, stream>>>(Mb, wo2, out);
}

// Round 8
// 211.726 us; speedup vs baseline: 2.5263x; 1.4519x over previous
//
#include <hip/hip_runtime.h>

#define D_MODEL 1024
#define SEQ     2048
#define BATCH   2
#define NHEADS  16
#define DK      64
#define NROWS   (BATCH*SEQ)   // 4096

typedef unsigned short u16;
typedef __bf16 bf16x8 __attribute__((ext_vector_type(8)));
typedef float  f32x4  __attribute__((ext_vector_type(4)));

__device__ __forceinline__ u16 f2bf(float f) {
    union { float f; unsigned u; } v; v.f = f;
    unsigned u = v.u;
    u += 0x7fffu + ((u >> 16) & 1);
    return (u16)(u >> 16);
}
__device__ __forceinline__ float bf2f(u16 h) {
    union { unsigned u; float f; } v; v.u = ((unsigned)h) << 16;
    return v.f;
}

__device__ __forceinline__ void gload_lds16(const u16* g, u16* l) {
    __builtin_amdgcn_global_load_lds(
        (const __attribute__((address_space(1))) void*)g,
        (__attribute__((address_space(3))) void*)l, 16, 0, 0);
}

// ---------- f32 [R][1024] -> bf16 split [R][2048] = [hi(1024) | lo(1024)] ----------
__global__ void cvt_split(const float* __restrict__ src, u16* __restrict__ dst, int total4) {
    int i = blockIdx.x * blockDim.x + threadIdx.x;
    if (i >= total4) return;
    int row = i >> 8;
    int c   = (i & 255) * 4;
    float4 v = *(const float4*)(src + (size_t)row * 1024 + c);
    u16 h0 = f2bf(v.x), h1 = f2bf(v.y), h2 = f2bf(v.z), h3 = f2bf(v.w);
    u16 l0 = f2bf(v.x - bf2f(h0)), l1 = f2bf(v.y - bf2f(h1));
    u16 l2 = f2bf(v.z - bf2f(h2)), l3 = f2bf(v.w - bf2f(h3));
    size_t b = (size_t)row * 2048;
    uint2 ph; ph.x = h0 | ((unsigned)h1 << 16); ph.y = h2 | ((unsigned)h3 << 16);
    uint2 pl; pl.x = l0 | ((unsigned)l1 << 16); pl.y = l2 | ((unsigned)l3 << 16);
    *(uint2*)&dst[b + c]        = ph;
    *(uint2*)&dst[b + 1024 + c] = pl;
}

__global__ void cvt_split4(const float* __restrict__ s0, const float* __restrict__ s1,
                           const float* __restrict__ s2, const float* __restrict__ s3,
                           u16* __restrict__ dst) {
    int i = blockIdx.x * blockDim.x + threadIdx.x;
    int wsel = i >> 18;
    int j = i & 262143;
    const float* src = wsel == 0 ? s0 : wsel == 1 ? s1 : wsel == 2 ? s2 : s3;
    int row = j >> 8;
    int c   = (j & 255) * 4;
    float4 v = *(const float4*)(src + (size_t)row * 1024 + c);
    u16 h0 = f2bf(v.x), h1 = f2bf(v.y), h2 = f2bf(v.z), h3 = f2bf(v.w);
    u16 l0 = f2bf(v.x - bf2f(h0)), l1 = f2bf(v.y - bf2f(h1));
    u16 l2 = f2bf(v.z - bf2f(h2)), l3 = f2bf(v.w - bf2f(h3));
    size_t b = (size_t)wsel * (2048 * 1024) + (size_t)row * 2048;
    uint2 ph; ph.x = h0 | ((unsigned)h1 << 16); ph.y = h2 | ((unsigned)h3 << 16);
    uint2 pl; pl.x = l0 | ((unsigned)l1 << 16); pl.y = l2 | ((unsigned)l3 << 16);
    *(uint2*)&dst[b + c]        = ph;
    *(uint2*)&dst[b + 1024 + c] = pl;
}

// ---------- merged QKV GEMM: split x split (3 MFMA), global_load_lds staging ----------
__global__ __launch_bounds__(256) void gemm_qkv(
    const u16* __restrict__ A2, const u16* __restrict__ W2,
    u16* __restrict__ Qp, u16* __restrict__ Kp, u16* __restrict__ Vt)
{
    __shared__ __align__(16) u16 Ash[128 * 32];
    __shared__ __align__(16) u16 Asl[128 * 32];
    __shared__ __align__(16) u16 Bsh[128 * 32];
    __shared__ __align__(16) u16 Bsl[128 * 32];

    const int m0  = blockIdx.x * 128;
    const int sel = blockIdx.y >> 3;
    const int n0  = (blockIdx.y & 7) * 128;
    const u16* B2 = W2 + (size_t)sel * (2048 * 1024);
    const int tid = threadIdx.x;
    const int lane = tid & 63;
    const int w    = tid >> 6;
    const int wr = w >> 1, wc = w & 1;
    const int fr = lane & 15;
    const int fk = (lane >> 4) * 8;
    const int rsub = lane >> 2;
    const int csub = (lane & 3) * 8;

    f32x4 acc[4][4];
#pragma unroll
    for (int i = 0; i < 4; ++i)
#pragma unroll
        for (int j = 0; j < 4; ++j) acc[i][j] = (f32x4){0.f, 0.f, 0.f, 0.f};

    for (int k0 = 0; k0 < 1024; k0 += 32) {
        __syncthreads();
        const u16* Ab = A2 + (size_t)(m0 + 16 * w + rsub) * 2048 + k0 + csub;
        const u16* Bb = B2 + (size_t)(n0 + 16 * w + rsub) * 2048 + k0 + csub;
#pragma unroll
        for (int half = 0; half < 2; ++half) {
            size_t ro = (size_t)(half * 64) * 2048;
            int lo = (half * 64 + 16 * w) * 32;
            gload_lds16(Ab + ro,        &Ash[lo]);
            gload_lds16(Ab + ro + 1024, &Asl[lo]);
            gload_lds16(Bb + ro,        &Bsh[lo]);
            gload_lds16(Bb + ro + 1024, &Bsl[lo]);
        }
        __syncthreads();

        bf16x8 ah[4], al[4], bh[4], bl[4];
#pragma unroll
        for (int i = 0; i < 4; ++i) {
            ah[i] = *(const bf16x8*)&Ash[(wr * 64 + i * 16 + fr) * 32 + fk];
            al[i] = *(const bf16x8*)&Asl[(wr * 64 + i * 16 + fr) * 32 + fk];
        }
#pragma unroll
        for (int j = 0; j < 4; ++j) {
            bh[j] = *(const bf16x8*)&Bsh[(wc * 64 + j * 16 + fr) * 32 + fk];
            bl[j] = *(const bf16x8*)&Bsl[(wc * 64 + j * 16 + fr) * 32 + fk];
        }
#pragma unroll
        for (int i = 0; i < 4; ++i)
#pragma unroll
            for (int j = 0; j < 4; ++j) {
                acc[i][j] = __builtin_amdgcn_mfma_f32_16x16x32_bf16(ah[i], bh[j], acc[i][j], 0, 0, 0);
                acc[i][j] = __builtin_amdgcn_mfma_f32_16x16x32_bf16(al[i], bh[j], acc[i][j], 0, 0, 0);
                acc[i][j] = __builtin_amdgcn_mfma_f32_16x16x32_bf16(ah[i], bl[j], acc[i][j], 0, 0, 0);
            }
    }

    const int r0 = (lane >> 4) * 4;
#pragma unroll
    for (int i = 0; i < 4; ++i) {
#pragma unroll
        for (int j = 0; j < 4; ++j) {
            int col = n0 + wc * 64 + j * 16 + fr;
#pragma unroll
            for (int r = 0; r < 4; ++r) {
                int row = m0 + wr * 64 + i * 16 + r0 + r;
                u16 v = f2bf(acc[i][j][r]);
                if (sel == 0)      Qp[(size_t)row * 1024 + col] = v;
                else if (sel == 1) Kp[(size_t)row * 1024 + col] = v;
                else               Vt[(size_t)col * NROWS + row] = v;
            }
        }
    }
}

// ---------- output GEMM: plain A x split B (2 MFMA), gload_lds staging, f32 out ----------
__global__ __launch_bounds__(256) void gemm_out(
    const u16* __restrict__ A, const u16* __restrict__ B2, float* __restrict__ Cout)
{
    __shared__ __align__(16) u16 Ash[128 * 32];
    __shared__ __align__(16) u16 Bsh[128 * 32];
    __shared__ __align__(16) u16 Bsl[128 * 32];

    const int m0 = blockIdx.x * 128;
    const int n0 = blockIdx.y * 128;
    const int tid = threadIdx.x;
    const int lane = tid & 63;
    const int w    = tid >> 6;
    const int wr = w >> 1, wc = w & 1;
    const int fr = lane & 15;
    const int fk = (lane >> 4) * 8;
    const int rsub = lane >> 2;
    const int csub = (lane & 3) * 8;

    f32x4 acc[4][4];
#pragma unroll
    for (int i = 0; i < 4; ++i)
#pragma unroll
        for (int j = 0; j < 4; ++j) acc[i][j] = (f32x4){0.f, 0.f, 0.f, 0.f};

    for (int k0 = 0; k0 < 1024; k0 += 32) {
        __syncthreads();
        const u16* Ab = A  + (size_t)(m0 + 16 * w + rsub) * 1024 + k0 + csub;
        const u16* Bb = B2 + (size_t)(n0 + 16 * w + rsub) * 2048 + k0 + csub;
#pragma unroll
        for (int half = 0; half < 2; ++half) {
            int lo = (half * 64 + 16 * w) * 32;
            gload_lds16(Ab + (size_t)(half * 64) * 1024,        &Ash[lo]);
            gload_lds16(Bb + (size_t)(half * 64) * 2048,        &Bsh[lo]);
            gload_lds16(Bb + (size_t)(half * 64) * 2048 + 1024, &Bsl[lo]);
        }
        __syncthreads();

        bf16x8 ah[4], bh[4], bl[4];
#pragma unroll
        for (int i = 0; i < 4; ++i)
            ah[i] = *(const bf16x8*)&Ash[(wr * 64 + i * 16 + fr) * 32 + fk];
#pragma unroll
        for (int j = 0; j < 4; ++j) {
            bh[j] = *(const bf16x8*)&Bsh[(wc * 64 + j * 16 + fr) * 32 + fk];
            bl[j] = *(const bf16x8*)&Bsl[(wc * 64 + j * 16 + fr) * 32 + fk];
        }
#pragma unroll
        for (int i = 0; i < 4; ++i)
#pragma unroll
            for (int j = 0; j < 4; ++j) {
                acc[i][j] = __builtin_amdgcn_mfma_f32_16x16x32_bf16(ah[i], bh[j], acc[i][j], 0, 0, 0);
                acc[i][j] = __builtin_amdgcn_mfma_f32_16x16x32_bf16(ah[i], bl[j], acc[i][j], 0, 0, 0);
            }
    }

    const int r0 = (lane >> 4) * 4;
#pragma unroll
    for (int i = 0; i < 4; ++i) {
#pragma unroll
        for (int j = 0; j < 4; ++j) {
            int col = n0 + wc * 64 + j * 16 + fr;
#pragma unroll
            for (int r = 0; r < 4; ++r)
                Cout[(size_t)(m0 + wr * 64 + i * 16 + r0 + r) * 1024 + col] = acc[i][j][r];
        }
    }
}

// ---------- RoPE in place on plain Q||K [8192][1024] ----------
__global__ void rope_plain(u16* __restrict__ qk, const int* __restrict__ pos) {
    int i = blockIdx.x * blockDim.x + threadIdx.x;
    int p = i & 511;
    int n = i >> 9;
    int s = n & 2047;
    int k = p & 31;
    int h = p >> 5;
    size_t base = (size_t)n * 1024 + h * DK + 2 * k;
    unsigned v = *(const unsigned*)&qk[base];
    float x0 = bf2f((u16)(v & 0xffff));
    float x1 = bf2f((u16)(v >> 16));
    float ang = (float)pos[s] * expf((float)k * -0.28782313662425575f);
    float c = cosf(ang), sn = sinf(ang);
    float y0 = x0 * c - x1 * sn;
    float y1 = x1 * c + x0 * sn;
    *(unsigned*)&qk[base] = (unsigned)f2bf(y0) | ((unsigned)f2bf(y1) << 16);
}

// ---------- causal flash attention v6: 8-wave, LDS-staged K+V, balanced chunks ----------
// 40 slots per (b,h): q-tile qt2 (128 rows) in group g=qt2>>2 has g+1 chunks of <=8 key tiles.
__global__ __launch_bounds__(512, 4) void attn_v6(
    const u16* __restrict__ Qp, const u16* __restrict__ Kp, const u16* __restrict__ Vt,
    u16* __restrict__ Op, float* __restrict__ mlbuf)
{
    const int slot = 39 - (int)blockIdx.x;    // longest chunks dispatch first
    const int h = blockIdx.y, b = blockIdx.z;
    int g, rr;
    if (slot < 4)       { g = 0; rr = slot; }
    else if (slot < 12) { g = 1; rr = slot - 4; }
    else if (slot < 24) { g = 2; rr = slot - 12; }
    else                { g = 3; rr = slot - 24; }
    const int qq  = rr / (g + 1);
    const int qt2 = 4 * g + qq;
    const int c   = rr - qq * (g + 1);

    const int tid  = threadIdx.x;
    const int lane = tid & 63;
    const int w    = tid >> 6;           // wave 0..7
    const int fr = lane & 15;
    const int fg = lane >> 4;
    const int bS = b * SEQ;
    const int hd = h * DK;
    const int qbase = qt2 * 128 + 16 * w;
    const int ntk = 2 * qt2 + 2;
    const int kt0 = 8 * c;
    const int kt1 = min(8 * c + 8, ntk);

    __shared__ __align__(16) u16 Kl[2][64 * 64];
    __shared__ __align__(16) u16 Vl[2][64 * 64];
    __shared__ __align__(16) u16 Plds[8][16][72];

    // staging: each wave stages 8 rows (1 KB) of each 64x64 tile; src col pre-swizzled
    const int srow = 8 * w + (lane >> 3);
    const int scol = (((lane & 7) ^ (lane >> 3)) * 8);
    const int swz  = (fr & 7) * 8;       // read-side XOR (u16 units)

    const u16* qrow = Qp + (size_t)(bS + qbase + fr) * 1024 + hd;
    bf16x8 qf0 = *(const bf16x8*)(qrow + fg * 8);
    bf16x8 qf1 = *(const bf16x8*)(qrow + 32 + fg * 8);

    f32x4 o[4];
#pragma unroll
    for (int j = 0; j < 4; ++j) o[j] = (f32x4){0.f, 0.f, 0.f, 0.f};
    float mrow = -1e30f, lrow = 0.f;

#define STAGE(BUF, KT) do { \
    int kb_ = (KT) * 64; \
    gload_lds16(Kp + (size_t)(bS + kb_ + srow) * 1024 + hd + scol, &Kl[BUF][(8 * w) * 64]); \
    gload_lds16(Vt + (size_t)(hd + srow) * NROWS + bS + kb_ + scol, &Vl[BUF][(8 * w) * 64]); \
} while (0)

    STAGE(0, kt0);
    __syncthreads();

    int cur = 0;
    for (int kt = kt0; kt < kt1; ++kt) {
        if (kt + 1 < kt1) STAGE(cur ^ 1, kt + 1);
        const int k0 = kt * 64;
        if (k0 <= qbase + 15) {          // wave-uniform participation
            // K A-frags from LDS (swizzled)
            bf16x8 kf[4][2];
#pragma unroll
            for (int t = 0; t < 4; ++t) {
                const u16* kr = &Kl[cur][(16 * t + fr) * 64];
                kf[t][0] = *(const bf16x8*)(kr + ((fg * 8) ^ swz));
                kf[t][1] = *(const bf16x8*)(kr + (((4 + fg) * 8) ^ swz));
            }
            f32x4 sc4[4];
#pragma unroll
            for (int t = 0; t < 4; ++t) {
                f32x4 a = (f32x4){0.f, 0.f, 0.f, 0.f};
                a = __builtin_amdgcn_mfma_f32_16x16x32_bf16(kf[t][0], qf0, a, 0, 0, 0);
                a = __builtin_amdgcn_mfma_f32_16x16x32_bf16(kf[t][1], qf1, a, 0, 0, 0);
                sc4[t] = a;
            }
            float p[4][4];
            if (k0 + 63 > qbase) {       // diagonal tile: mask
#pragma unroll
                for (int t = 0; t < 4; ++t)
#pragma unroll
                    for (int r = 0; r < 4; ++r) {
                        float v = sc4[t][r] * 0.125f;
                        if (k0 + 16 * t + 4 * fg + r > qbase + fr) v = -1e30f;
                        p[t][r] = v;
                    }
            } else {
#pragma unroll
                for (int t = 0; t < 4; ++t)
#pragma unroll
                    for (int r = 0; r < 4; ++r) p[t][r] = sc4[t][r] * 0.125f;
            }
            float mx = p[0][0];
#pragma unroll
            for (int t = 0; t < 4; ++t)
#pragma unroll
                for (int r = 0; r < 4; ++r) mx = fmaxf(mx, p[t][r]);
            mx = fmaxf(mx, __shfl_xor(mx, 16));
            mx = fmaxf(mx, __shfl_xor(mx, 32));
            float mnew = fmaxf(mrow, mx);
            float scf = __expf(mrow - mnew);
            mrow = mnew;
            float rs = 0.f;
#pragma unroll
            for (int t = 0; t < 4; ++t)
#pragma unroll
                for (int r = 0; r < 4; ++r) {
                    p[t][r] = __expf(p[t][r] - mnew);
                    rs += p[t][r];
                }
            rs += __shfl_xor(rs, 16);
            rs += __shfl_xor(rs, 32);
            lrow = lrow * scf + rs;
            float scr[4];
#pragma unroll
            for (int r = 0; r < 4; ++r) scr[r] = __shfl(scf, 4 * fg + r);
#pragma unroll
            for (int j = 0; j < 4; ++j)
#pragma unroll
                for (int r = 0; r < 4; ++r) o[j][r] *= scr[r];
#pragma unroll
            for (int t = 0; t < 4; ++t)
#pragma unroll
                for (int r = 0; r < 4; ++r)
                    Plds[w][fr][16 * t + 4 * fg + r] = f2bf(p[t][r]);
            bf16x8 pf0 = *(const bf16x8*)&Plds[w][fr][fg * 8];
            bf16x8 pf1 = *(const bf16x8*)&Plds[w][fr][32 + fg * 8];
            // V B-frags from LDS (swizzled)
#pragma unroll
            for (int j = 0; j < 4; ++j) {
                const u16* vr = &Vl[cur][(16 * j + fr) * 64];
                bf16x8 v0 = *(const bf16x8*)(vr + ((fg * 8) ^ swz));
                bf16x8 v1 = *(const bf16x8*)(vr + (((4 + fg) * 8) ^ swz));
                o[j] = __builtin_amdgcn_mfma_f32_16x16x32_bf16(pf0, v0, o[j], 0, 0, 0);
                o[j] = __builtin_amdgcn_mfma_f32_16x16x32_bf16(pf1, v1, o[j], 0, 0, 0);
            }
        }
        __syncthreads();
        cur ^= 1;
    }
#undef STAGE

    const int slotg = (b * NHEADS + h) * 40 + slot;
#pragma unroll
    for (int r = 0; r < 4; ++r) {
        int rrel = 16 * w + 4 * fg + r;
#pragma unroll
        for (int j = 0; j < 4; ++j)
            Op[((size_t)slotg * 128 + rrel) * 64 + 16 * j + fr] = f2bf(o[j][r]);
    }
    if (fg == 0) {
        float* pp = mlbuf + ((size_t)slotg * 128 + 16 * w + fr) * 2;
        pp[0] = mrow;
        pp[1] = lrow;
    }
}

// ---------- combine up-to-4 split-K partials -> Mb ----------
__global__ void attn_combine3(const u16* __restrict__ Op, const float* __restrict__ mlbuf,
                              u16* __restrict__ Mb) {
    int i = blockIdx.x * blockDim.x + threadIdx.x;   // 4096*128 = 524288
    int row = i >> 7;            // 0..4095
    int c8  = (i & 127) * 8;     // col 0..1016
    int h   = c8 >> 6;
    int s   = row & 2047;
    int b   = row >> 11;
    int qt2 = s >> 7;
    int g   = qt2 >> 2;
    int nch = g + 1;
    int slot0 = (b * NHEADS + h) * 40 + 2 * g * (g + 1) + (qt2 & 3) * (g + 1);
    int rrel = s & 127, crel = c8 & 63;

    float mv[4], lv[4];
    float m = -1e30f;
    for (int k = 0; k < nch; ++k) {
        const float* pp = mlbuf + ((size_t)(slot0 + k) * 128 + rrel) * 2;
        mv[k] = pp[0]; lv[k] = pp[1];
        m = fmaxf(m, mv[k]);
    }
    float L = 0.f;
    for (int k = 0; k < nch; ++k) {
        mv[k] = __expf(mv[k] - m);
        L += lv[k] * mv[k];
    }
    float acc[8];
#pragma unroll
    for (int jj = 0; jj < 8; ++jj) acc[jj] = 0.f;
    for (int k = 0; k < nch; ++k) {
        float wgt = mv[k];
        uint4 u = *(const uint4*)(Op + ((size_t)(slot0 + k) * 128 + rrel) * 64 + crel);
        const unsigned* wrd = (const unsigned*)&u;
#pragma unroll
        for (int kk = 0; kk < 4; ++kk) {
            acc[2 * kk]     += wgt * bf2f((u16)(wrd[kk] & 0xffff));
            acc[2 * kk + 1] += wgt * bf2f((u16)(wrd[kk] >> 16));
        }
    }
    float inv = 1.0f / L;
    unsigned ou[4];
#pragma unroll
    for (int kk = 0; kk < 4; ++kk)
        ou[kk] = (unsigned)f2bf(acc[2 * kk] * inv) | ((unsigned)f2bf(acc[2 * kk + 1] * inv) << 16);
    *(uint4*)(Mb + (size_t)row * 1024 + c8) = *(uint4*)ou;
}

extern "C" void kernel_launch(void* const* d_in, const int* in_sizes, int n_in,
                              void* d_out, int out_size, void* d_ws, size_t ws_size,
                              hipStream_t stream) {
    const float* x   = (const float*)d_in[0];
    const int*   pos = (const int*)d_in[1];
    const float* wq  = (const float*)d_in[2];
    const float* wk  = (const float*)d_in[3];
    const float* wv  = (const float*)d_in[4];
    const float* wo  = (const float*)d_in[5];
    float* out = (float*)d_out;

    char* ws = (char*)d_ws;
    u16* x2  = (u16*)(ws);                    // 16 MB split [4096][2048]; dead after QKV
    u16* w2  = (u16*)(ws + (16ull << 20));    // 16 MB: wq2|wk2|wv2|wo2 split
    u16* wo2 = w2 + 3 * 2048 * 1024;          // [28,32) — survives to the end
    u16* Qp  = (u16*)(ws + (32ull << 20));    //  8 MB plain [4096][1024]
    u16* Kp  = (u16*)(ws + (40ull << 20));    //  8 MB plain
    u16* Vt  = (u16*)(ws + (48ull << 20));    //  8 MB plain transposed [1024][4096]
    u16* Mb  = (u16*)(ws + (56ull << 20));    //  8 MB plain [4096][1024]
    u16* Op  = (u16*)(ws);                    // 21 MB partials (reuses dead x2/wq2/wk2-head)
    float* mlbuf = (float*)(ws + (21ull << 20)); // 1.3 MB (dead wk2 region)

    // 1) convert inputs
    cvt_split<<<4096, 256, 0, stream>>>(x, x2, NROWS * 256);
    cvt_split4<<<4096, 256, 0, stream>>>(wq, wk, wv, wo, w2);

    // 2) merged QKV projection
    gemm_qkv<<<dim3(NROWS / 128, 24), 256, 0, stream>>>(x2, w2, Qp, Kp, Vt);

    // 3) RoPE in place
    rope_plain<<<16384, 256, 0, stream>>>(Qp, pos);

    // 4) causal flash attention v6 (LDS-staged K+V, balanced chunks) + combine
    attn_v6<<<dim3(40, NHEADS, BATCH), 512, 0, stream>>>(Qp, Kp, Vt, Op, mlbuf);
    attn_combine3<<<2048, 256, 0, stream>>>(Op, mlbuf, Mb);

    // 5) output projection
    gemm_out<<<dim3(NROWS / 128, 8), 256, 0, stream>>>(Mb, wo2, out);
}

// Round 9
// 153.471 us; speedup vs baseline: 3.4852x; 1.3796x over previous
//
#include <hip/hip_runtime.h>

#define D_MODEL 1024
#define SEQ     2048
#define BATCH   2
#define NHEADS  16
#define DK      64
#define NROWS   (BATCH*SEQ)   // 4096

typedef unsigned short u16;
typedef __bf16 bf16x8 __attribute__((ext_vector_type(8)));
typedef float  f32x4  __attribute__((ext_vector_type(4)));

__device__ __forceinline__ u16 f2bf(float f) {
    union { float f; unsigned u; } v; v.f = f;
    unsigned u = v.u;
    u += 0x7fffu + ((u >> 16) & 1);
    return (u16)(u >> 16);
}
__device__ __forceinline__ float bf2f(u16 h) {
    union { unsigned u; float f; } v; v.u = ((unsigned)h) << 16;
    return v.f;
}

__device__ __forceinline__ void gload_lds16(const u16* g, u16* l) {
    __builtin_amdgcn_global_load_lds(
        (const __attribute__((address_space(1))) void*)g,
        (__attribute__((address_space(3))) void*)l, 16, 0, 0);
}

// ---------- f32 -> plain bf16: x (4096 rows) + 4 weights (4096 rows) ----------
__global__ void cvt_bf16_all(const float* __restrict__ x,
                             const float* __restrict__ w0, const float* __restrict__ w1,
                             const float* __restrict__ w2, const float* __restrict__ w3,
                             u16* __restrict__ xb, u16* __restrict__ wb) {
    int i = blockIdx.x * blockDim.x + threadIdx.x;   // 8192 rows * 256 chunks
    int row = i >> 8;
    int c   = (i & 255) * 4;
    const float* src; u16* dst;
    if (row < 4096) {
        src = x + (size_t)row * 1024;
        dst = xb + (size_t)row * 1024;
    } else {
        int r2 = row - 4096;
        int ws = r2 >> 10;
        int rr = r2 & 1023;
        const float* wsrc = ws == 0 ? w0 : ws == 1 ? w1 : ws == 2 ? w2 : w3;
        src = wsrc + (size_t)rr * 1024;
        dst = wb + ((size_t)ws << 20) + (size_t)rr * 1024;
    }
    float4 v = *(const float4*)(src + c);
    uint2 o;
    o.x = (unsigned)f2bf(v.x) | ((unsigned)f2bf(v.y) << 16);
    o.y = (unsigned)f2bf(v.z) | ((unsigned)f2bf(v.w) << 16);
    *(uint2*)(dst + c) = o;
}

// ---------- merged QKV GEMM: plain bf16 (1 MFMA), global_load_lds staging ----------
// blockIdx.y: [0,8)=Q, [8,16)=K, [16,24)=V(transposed out)
__global__ __launch_bounds__(256) void gemm_qkv_p(
    const u16* __restrict__ A, const u16* __restrict__ W,
    u16* __restrict__ Qp, u16* __restrict__ Kp, u16* __restrict__ Vt)
{
    __shared__ __align__(16) u16 Ash[128 * 32];
    __shared__ __align__(16) u16 Bsh[128 * 32];

    const int m0  = blockIdx.x * 128;
    const int sel = blockIdx.y >> 3;
    const int n0  = (blockIdx.y & 7) * 128;
    const u16* B = W + ((size_t)sel << 20);
    const int tid = threadIdx.x;
    const int lane = tid & 63;
    const int w    = tid >> 6;
    const int wr = w >> 1, wc = w & 1;
    const int fr = lane & 15;
    const int fk = (lane >> 4) * 8;
    const int rsub = lane >> 2;
    const int csub = (lane & 3) * 8;

    f32x4 acc[4][4];
#pragma unroll
    for (int i = 0; i < 4; ++i)
#pragma unroll
        for (int j = 0; j < 4; ++j) acc[i][j] = (f32x4){0.f, 0.f, 0.f, 0.f};

    for (int k0 = 0; k0 < 1024; k0 += 32) {
        __syncthreads();
        const u16* Ab = A + (size_t)(m0 + 16 * w + rsub) * 1024 + k0 + csub;
        const u16* Bb = B + (size_t)(n0 + 16 * w + rsub) * 1024 + k0 + csub;
#pragma unroll
        for (int half = 0; half < 2; ++half) {
            size_t ro = (size_t)(half * 64) * 1024;
            int lo = (half * 64 + 16 * w) * 32;
            gload_lds16(Ab + ro, &Ash[lo]);
            gload_lds16(Bb + ro, &Bsh[lo]);
        }
        __syncthreads();

        bf16x8 ah[4], bh[4];
#pragma unroll
        for (int i = 0; i < 4; ++i)
            ah[i] = *(const bf16x8*)&Ash[(wr * 64 + i * 16 + fr) * 32 + fk];
#pragma unroll
        for (int j = 0; j < 4; ++j)
            bh[j] = *(const bf16x8*)&Bsh[(wc * 64 + j * 16 + fr) * 32 + fk];
#pragma unroll
        for (int i = 0; i < 4; ++i)
#pragma unroll
            for (int j = 0; j < 4; ++j)
                acc[i][j] = __builtin_amdgcn_mfma_f32_16x16x32_bf16(ah[i], bh[j], acc[i][j], 0, 0, 0);
    }

    const int r0 = (lane >> 4) * 4;
#pragma unroll
    for (int i = 0; i < 4; ++i) {
#pragma unroll
        for (int j = 0; j < 4; ++j) {
            int col = n0 + wc * 64 + j * 16 + fr;
#pragma unroll
            for (int r = 0; r < 4; ++r) {
                int row = m0 + wr * 64 + i * 16 + r0 + r;
                u16 v = f2bf(acc[i][j][r]);
                if (sel == 0)      Qp[(size_t)row * 1024 + col] = v;
                else if (sel == 1) Kp[(size_t)row * 1024 + col] = v;
                else               Vt[(size_t)col * NROWS + row] = v;
            }
        }
    }
}

// ---------- output GEMM: plain x plain (1 MFMA), gload_lds staging, f32 out ----------
__global__ __launch_bounds__(256) void gemm_out_p(
    const u16* __restrict__ A, const u16* __restrict__ B, float* __restrict__ Cout)
{
    __shared__ __align__(16) u16 Ash[128 * 32];
    __shared__ __align__(16) u16 Bsh[128 * 32];

    const int m0 = blockIdx.x * 128;
    const int n0 = blockIdx.y * 128;
    const int tid = threadIdx.x;
    const int lane = tid & 63;
    const int w    = tid >> 6;
    const int wr = w >> 1, wc = w & 1;
    const int fr = lane & 15;
    const int fk = (lane >> 4) * 8;
    const int rsub = lane >> 2;
    const int csub = (lane & 3) * 8;

    f32x4 acc[4][4];
#pragma unroll
    for (int i = 0; i < 4; ++i)
#pragma unroll
        for (int j = 0; j < 4; ++j) acc[i][j] = (f32x4){0.f, 0.f, 0.f, 0.f};

    for (int k0 = 0; k0 < 1024; k0 += 32) {
        __syncthreads();
        const u16* Ab = A + (size_t)(m0 + 16 * w + rsub) * 1024 + k0 + csub;
        const u16* Bb = B + (size_t)(n0 + 16 * w + rsub) * 1024 + k0 + csub;
#pragma unroll
        for (int half = 0; half < 2; ++half) {
            size_t ro = (size_t)(half * 64) * 1024;
            int lo = (half * 64 + 16 * w) * 32;
            gload_lds16(Ab + ro, &Ash[lo]);
            gload_lds16(Bb + ro, &Bsh[lo]);
        }
        __syncthreads();

        bf16x8 ah[4], bh[4];
#pragma unroll
        for (int i = 0; i < 4; ++i)
            ah[i] = *(const bf16x8*)&Ash[(wr * 64 + i * 16 + fr) * 32 + fk];
#pragma unroll
        for (int j = 0; j < 4; ++j)
            bh[j] = *(const bf16x8*)&Bsh[(wc * 64 + j * 16 + fr) * 32 + fk];
#pragma unroll
        for (int i = 0; i < 4; ++i)
#pragma unroll
            for (int j = 0; j < 4; ++j)
                acc[i][j] = __builtin_amdgcn_mfma_f32_16x16x32_bf16(ah[i], bh[j], acc[i][j], 0, 0, 0);
    }

    const int r0 = (lane >> 4) * 4;
#pragma unroll
    for (int i = 0; i < 4; ++i) {
#pragma unroll
        for (int j = 0; j < 4; ++j) {
            int col = n0 + wc * 64 + j * 16 + fr;
#pragma unroll
            for (int r = 0; r < 4; ++r)
                Cout[(size_t)(m0 + wr * 64 + i * 16 + r0 + r) * 1024 + col] = acc[i][j][r];
        }
    }
}

// ---------- RoPE in place on plain Q||K [8192][1024] ----------
__global__ void rope_plain(u16* __restrict__ qk, const int* __restrict__ pos) {
    int i = blockIdx.x * blockDim.x + threadIdx.x;
    int p = i & 511;
    int n = i >> 9;
    int s = n & 2047;
    int k = p & 31;
    int h = p >> 5;
    size_t base = (size_t)n * 1024 + h * DK + 2 * k;
    unsigned v = *(const unsigned*)&qk[base];
    float x0 = bf2f((u16)(v & 0xffff));
    float x1 = bf2f((u16)(v >> 16));
    float ang = (float)pos[s] * expf((float)k * -0.28782313662425575f);
    float c = cosf(ang), sn = sinf(ang);
    float y0 = x0 * c - x1 * sn;
    float y1 = x1 * c + x0 * sn;
    *(unsigned*)&qk[base] = (unsigned)f2bf(y0) | ((unsigned)f2bf(y1) << 16);
}

// ---------- causal flash attention v6: 8-wave, LDS-staged K+V, balanced chunks ----------
__global__ __launch_bounds__(512, 4) void attn_v6(
    const u16* __restrict__ Qp, const u16* __restrict__ Kp, const u16* __restrict__ Vt,
    u16* __restrict__ Op, float* __restrict__ mlbuf)
{
    const int slot = 39 - (int)blockIdx.x;
    const int h = blockIdx.y, b = blockIdx.z;
    int g, rr;
    if (slot < 4)       { g = 0; rr = slot; }
    else if (slot < 12) { g = 1; rr = slot - 4; }
    else if (slot < 24) { g = 2; rr = slot - 12; }
    else                { g = 3; rr = slot - 24; }
    const int qq  = rr / (g + 1);
    const int qt2 = 4 * g + qq;
    const int c   = rr - qq * (g + 1);

    const int tid  = threadIdx.x;
    const int lane = tid & 63;
    const int w    = tid >> 6;
    const int fr = lane & 15;
    const int fg = lane >> 4;
    const int bS = b * SEQ;
    const int hd = h * DK;
    const int qbase = qt2 * 128 + 16 * w;
    const int ntk = 2 * qt2 + 2;
    const int kt0 = 8 * c;
    const int kt1 = min(8 * c + 8, ntk);

    __shared__ __align__(16) u16 Kl[2][64 * 64];
    __shared__ __align__(16) u16 Vl[2][64 * 64];
    __shared__ __align__(16) u16 Plds[8][16][72];

    const int srow = 8 * w + (lane >> 3);
    const int scol = (((lane & 7) ^ (lane >> 3)) * 8);
    const int swz  = (fr & 7) * 8;

    const u16* qrow = Qp + (size_t)(bS + qbase + fr) * 1024 + hd;
    bf16x8 qf0 = *(const bf16x8*)(qrow + fg * 8);
    bf16x8 qf1 = *(const bf16x8*)(qrow + 32 + fg * 8);

    f32x4 o[4];
#pragma unroll
    for (int j = 0; j < 4; ++j) o[j] = (f32x4){0.f, 0.f, 0.f, 0.f};
    float mrow = -1e30f, lrow = 0.f;

#define STAGE(BUF, KT) do { \
    int kb_ = (KT) * 64; \
    gload_lds16(Kp + (size_t)(bS + kb_ + srow) * 1024 + hd + scol, &Kl[BUF][(8 * w) * 64]); \
    gload_lds16(Vt + (size_t)(hd + srow) * NROWS + bS + kb_ + scol, &Vl[BUF][(8 * w) * 64]); \
} while (0)

    STAGE(0, kt0);
    __syncthreads();

    int cur = 0;
    for (int kt = kt0; kt < kt1; ++kt) {
        if (kt + 1 < kt1) STAGE(cur ^ 1, kt + 1);
        const int k0 = kt * 64;
        if (k0 <= qbase + 15) {
            bf16x8 kf[4][2];
#pragma unroll
            for (int t = 0; t < 4; ++t) {
                const u16* kr = &Kl[cur][(16 * t + fr) * 64];
                kf[t][0] = *(const bf16x8*)(kr + ((fg * 8) ^ swz));
                kf[t][1] = *(const bf16x8*)(kr + (((4 + fg) * 8) ^ swz));
            }
            f32x4 sc4[4];
#pragma unroll
            for (int t = 0; t < 4; ++t) {
                f32x4 a = (f32x4){0.f, 0.f, 0.f, 0.f};
                a = __builtin_amdgcn_mfma_f32_16x16x32_bf16(kf[t][0], qf0, a, 0, 0, 0);
                a = __builtin_amdgcn_mfma_f32_16x16x32_bf16(kf[t][1], qf1, a, 0, 0, 0);
                sc4[t] = a;
            }
            float p[4][4];
            if (k0 + 63 > qbase) {
#pragma unroll
                for (int t = 0; t < 4; ++t)
#pragma unroll
                    for (int r = 0; r < 4; ++r) {
                        float v = sc4[t][r] * 0.125f;
                        if (k0 + 16 * t + 4 * fg + r > qbase + fr) v = -1e30f;
                        p[t][r] = v;
                    }
            } else {
#pragma unroll
                for (int t = 0; t < 4; ++t)
#pragma unroll
                    for (int r = 0; r < 4; ++r) p[t][r] = sc4[t][r] * 0.125f;
            }
            float mx = p[0][0];
#pragma unroll
            for (int t = 0; t < 4; ++t)
#pragma unroll
                for (int r = 0; r < 4; ++r) mx = fmaxf(mx, p[t][r]);
            mx = fmaxf(mx, __shfl_xor(mx, 16));
            mx = fmaxf(mx, __shfl_xor(mx, 32));
            float mnew = fmaxf(mrow, mx);
            float scf = __expf(mrow - mnew);
            mrow = mnew;
            float rs = 0.f;
#pragma unroll
            for (int t = 0; t < 4; ++t)
#pragma unroll
                for (int r = 0; r < 4; ++r) {
                    p[t][r] = __expf(p[t][r] - mnew);
                    rs += p[t][r];
                }
            rs += __shfl_xor(rs, 16);
            rs += __shfl_xor(rs, 32);
            lrow = lrow * scf + rs;
            float scr[4];
#pragma unroll
            for (int r = 0; r < 4; ++r) scr[r] = __shfl(scf, 4 * fg + r);
#pragma unroll
            for (int j = 0; j < 4; ++j)
#pragma unroll
                for (int r = 0; r < 4; ++r) o[j][r] *= scr[r];
#pragma unroll
            for (int t = 0; t < 4; ++t)
#pragma unroll
                for (int r = 0; r < 4; ++r)
                    Plds[w][fr][16 * t + 4 * fg + r] = f2bf(p[t][r]);
            bf16x8 pf0 = *(const bf16x8*)&Plds[w][fr][fg * 8];
            bf16x8 pf1 = *(const bf16x8*)&Plds[w][fr][32 + fg * 8];
#pragma unroll
            for (int j = 0; j < 4; ++j) {
                const u16* vr = &Vl[cur][(16 * j + fr) * 64];
                bf16x8 v0 = *(const bf16x8*)(vr + ((fg * 8) ^ swz));
                bf16x8 v1 = *(const bf16x8*)(vr + (((4 + fg) * 8) ^ swz));
                o[j] = __builtin_amdgcn_mfma_f32_16x16x32_bf16(pf0, v0, o[j], 0, 0, 0);
                o[j] = __builtin_amdgcn_mfma_f32_16x16x32_bf16(pf1, v1, o[j], 0, 0, 0);
            }
        }
        __syncthreads();
        cur ^= 1;
    }
#undef STAGE

    const int slotg = (b * NHEADS + h) * 40 + slot;
#pragma unroll
    for (int r = 0; r < 4; ++r) {
        int rrel = 16 * w + 4 * fg + r;
#pragma unroll
        for (int j = 0; j < 4; ++j)
            Op[((size_t)slotg * 128 + rrel) * 64 + 16 * j + fr] = f2bf(o[j][r]);
    }
    if (fg == 0) {
        float* pp = mlbuf + ((size_t)slotg * 128 + 16 * w + fr) * 2;
        pp[0] = mrow;
        pp[1] = lrow;
    }
}

// ---------- combine up-to-4 split-K partials -> Mb ----------
__global__ void attn_combine3(const u16* __restrict__ Op, const float* __restrict__ mlbuf,
                              u16* __restrict__ Mb) {
    int i = blockIdx.x * blockDim.x + threadIdx.x;
    int row = i >> 7;
    int c8  = (i & 127) * 8;
    int h   = c8 >> 6;
    int s   = row & 2047;
    int b   = row >> 11;
    int qt2 = s >> 7;
    int g   = qt2 >> 2;
    int nch = g + 1;
    int slot0 = (b * NHEADS + h) * 40 + 2 * g * (g + 1) + (qt2 & 3) * (g + 1);
    int rrel = s & 127, crel = c8 & 63;

    float mv[4], lv[4];
    float m = -1e30f;
    for (int k = 0; k < nch; ++k) {
        const float* pp = mlbuf + ((size_t)(slot0 + k) * 128 + rrel) * 2;
        mv[k] = pp[0]; lv[k] = pp[1];
        m = fmaxf(m, mv[k]);
    }
    float L = 0.f;
    for (int k = 0; k < nch; ++k) {
        mv[k] = __expf(mv[k] - m);
        L += lv[k] * mv[k];
    }
    float acc[8];
#pragma unroll
    for (int jj = 0; jj < 8; ++jj) acc[jj] = 0.f;
    for (int k = 0; k < nch; ++k) {
        float wgt = mv[k];
        uint4 u = *(const uint4*)(Op + ((size_t)(slot0 + k) * 128 + rrel) * 64 + crel);
        const unsigned* wrd = (const unsigned*)&u;
#pragma unroll
        for (int kk = 0; kk < 4; ++kk) {
            acc[2 * kk]     += wgt * bf2f((u16)(wrd[kk] & 0xffff));
            acc[2 * kk + 1] += wgt * bf2f((u16)(wrd[kk] >> 16));
        }
    }
    float inv = 1.0f / L;
    unsigned ou[4];
#pragma unroll
    for (int kk = 0; kk < 4; ++kk)
        ou[kk] = (unsigned)f2bf(acc[2 * kk] * inv) | ((unsigned)f2bf(acc[2 * kk + 1] * inv) << 16);
    *(uint4*)(Mb + (size_t)row * 1024 + c8) = *(uint4*)ou;
}

extern "C" void kernel_launch(void* const* d_in, const int* in_sizes, int n_in,
                              void* d_out, int out_size, void* d_ws, size_t ws_size,
                              hipStream_t stream) {
    const float* x   = (const float*)d_in[0];
    const int*   pos = (const int*)d_in[1];
    const float* wq  = (const float*)d_in[2];
    const float* wk  = (const float*)d_in[3];
    const float* wv  = (const float*)d_in[4];
    const float* wo  = (const float*)d_in[5];
    float* out = (float*)d_out;

    char* ws = (char*)d_ws;
    u16* xb  = (u16*)(ws);                    //  8 MB plain [4096][1024]; dead after QKV
    u16* wb  = (u16*)(ws + (24ull << 20));    //  8 MB: wq|wk|wv|wo plain, 2 MB each
    u16* wob = wb + 3 * (1 << 20);            //  [30,32) — survives to the end
    u16* Qp  = (u16*)(ws + (32ull << 20));    //  8 MB plain [4096][1024]
    u16* Kp  = (u16*)(ws + (40ull << 20));    //  8 MB plain
    u16* Vt  = (u16*)(ws + (48ull << 20));    //  8 MB plain transposed [1024][4096]
    u16* Mb  = (u16*)(ws + (56ull << 20));    //  8 MB plain [4096][1024]
    u16* Op  = (u16*)(ws);                    // 21 MB partials (reuses dead xb + gap)
    float* mlbuf = (float*)(ws + (21ull << 20)); // 1.3 MB [21, 22.3) — below wb

    // 1) convert x + 4 weights to plain bf16 (one launch)
    cvt_bf16_all<<<8192, 256, 0, stream>>>(x, wq, wk, wv, wo, xb, wb);

    // 2) merged QKV projection (plain bf16, 1-MFMA)
    gemm_qkv_p<<<dim3(NROWS / 128, 24), 256, 0, stream>>>(xb, wb, Qp, Kp, Vt);

    // 3) RoPE in place
    rope_plain<<<16384, 256, 0, stream>>>(Qp, pos);

    // 4) causal flash attention v6 + combine
    attn_v6<<<dim3(40, NHEADS, BATCH), 512, 0, stream>>>(Qp, Kp, Vt, Op, mlbuf);
    attn_combine3<<<2048, 256, 0, stream>>>(Op, mlbuf, Mb);

    // 5) output projection (plain, f32 out)
    gemm_out_p<<<dim3(NROWS / 128, 8), 256, 0, stream>>>(Mb, wob, out);
}